// Round 16
// baseline (1969.045 us; speedup 1.0000x reference)
//
#include <hip/hip_runtime.h>
#include <hip/hip_bf16.h>

#define SEQ 128
#define BAT 64
#define VOC 10000
#define EMBD 512
#define HID 512
#define BH (BAT*HID)                  // 32768
// workspace layout (floats)
#define PRE0_OFF 0
#define H0_OFF   ((size_t)SEQ*BH)                 // pre0: 128*BH
#define H1_OFF   (H0_OFF + (size_t)(SEQ+1)*BH)
#define FLAGS_OFF (H1_OFF + (size_t)(SEQ+1)*BH)   // 256 uints: fl1[0..63], fl2[64..191], qctr[192..193]
#define CONV_OFF (FLAGS_OFF + 256)                // bf16 weight arrays
#define LOGITS_N ((size_t)SEQ*BAT*VOC)            // 81,920,000 (in d_out)
// conv region (ushorts): wy_hi 5,120,000 + wih0_hi 262,144
#define CONV_USHORTS 5382144ull
#define WS_NEED_FLOATS (CONV_OFF + CONV_USHORTS/2)

#define N_REC  192
#define N_WORK 200

typedef __attribute__((ext_vector_type(8))) __bf16 bf16x8;
typedef __attribute__((ext_vector_type(4))) float f32x4;

__global__ __launch_bounds__(256) void init_state_k(const float* __restrict__ hidden,
                                                    float* __restrict__ h0_0,
                                                    float* __restrict__ h1_0,
                                                    unsigned* __restrict__ flags) {
    int i = blockIdx.x * 256 + threadIdx.x;
    if (i < 256) flags[i] = 0u;   // includes queue counters at [192],[193]
    if (i < BH) { h0_0[i] = hidden[i]; h1_0[i] = hidden[BH + i]; }
}

// fp32 GEMM fallback (only if ws too small for bf16-split path).
__global__ __launch_bounds__(256) void gemm_nt_k(
    const float* __restrict__ A, const int* __restrict__ tok,
    const float* __restrict__ Bm,
    const float* __restrict__ bias0, const float* __restrict__ bias1,
    float* __restrict__ C, int N, int K, int ldc)
{
    __shared__ float As[32][132];
    __shared__ float Bs[32][132];
    __shared__ int toks[128];

    const int tid = threadIdx.x;
    const int r0 = blockIdx.x * 128;
    const int c0 = blockIdx.y * 128;

    if (tok != nullptr && tid < 128) toks[tid] = tok[r0 + tid];
    __syncthreads();

    const int tn = tid & 15;
    const int tm = tid >> 4;
    const int m0 = tm * 8, n0 = tn * 8;

    float acc[8][8];
#pragma unroll
    for (int i = 0; i < 8; ++i)
#pragma unroll
        for (int j = 0; j < 8; ++j) acc[i][j] = 0.f;

    for (int k0 = 0; k0 < K; k0 += 32) {
#pragma unroll
        for (int p = 0; p < 4; ++p) {
            int idx = p * 256 + tid;
            int row = idx >> 3;
            int kq  = (idx & 7) << 2;
            size_t arow = tok ? (size_t)toks[row] : (size_t)(r0 + row);
            float4 a = *(const float4*)(A + arow * (size_t)K + k0 + kq);
            As[kq+0][row] = a.x; As[kq+1][row] = a.y;
            As[kq+2][row] = a.z; As[kq+3][row] = a.w;
            int gc = c0 + row;
            float4 b = make_float4(0.f, 0.f, 0.f, 0.f);
            if (gc < N) b = *(const float4*)(Bm + (size_t)gc * K + k0 + kq);
            Bs[kq+0][row] = b.x; Bs[kq+1][row] = b.y;
            Bs[kq+2][row] = b.z; Bs[kq+3][row] = b.w;
        }
        __syncthreads();
#pragma unroll 8
        for (int k = 0; k < 32; ++k) {
            float4 a0 = *(const float4*)&As[k][m0];
            float4 a1 = *(const float4*)&As[k][m0 + 4];
            float4 b0 = *(const float4*)&Bs[k][n0];
            float4 b1 = *(const float4*)&Bs[k][n0 + 4];
            float am[8] = {a0.x,a0.y,a0.z,a0.w,a1.x,a1.y,a1.z,a1.w};
            float bn[8] = {b0.x,b0.y,b0.z,b0.w,b1.x,b1.y,b1.z,b1.w};
#pragma unroll
            for (int i = 0; i < 8; ++i)
#pragma unroll
                for (int j = 0; j < 8; ++j) acc[i][j] += am[i] * bn[j];
        }
        __syncthreads();
    }

    const bool full = (c0 + 128 <= N);
#pragma unroll
    for (int i = 0; i < 8; ++i) {
        size_t r = (size_t)(r0 + m0 + i);
        float* crow = C + r * (size_t)ldc;
#pragma unroll
        for (int j = 0; j < 8; ++j) {
            int c = c0 + n0 + j;
            if (full || c < N) {
                float v = acc[i][j];
                if (bias0) v += bias0[c];
                if (bias1) v += bias1[c];
                crow[c] = v;
            }
        }
    }
}

#define BFLY(S, N)                                                     \
    {                                                                  \
        _Pragma("unroll")                                              \
        for (int i = 0; i < N; ++i) {                                  \
            float lo_ = a[i], hi_ = a[i + N];                          \
            float send_ = (lane & S) ? lo_ : hi_;                      \
            float recv_ = __shfl_xor(send_, S);                       \
            a[i] = ((lane & S) ? hi_ : lo_) + recv_;                   \
        }                                                              \
    }

__device__ __forceinline__ unsigned bf16_rne(float x) {
    unsigned u = __float_as_uint(x);
    unsigned r = u + 0x7fffu + ((u >> 16) & 1u);
    return r >> 16;
}

// ---- v4 recurrence body, parameterized by task id (0..191) ----
__device__ __forceinline__ void recurrence_body(
    int blk,
    const float* __restrict__ pre0, const float* __restrict__ W_hh0,
    const float* __restrict__ W_in, const float* __restrict__ b_in,
    const float* __restrict__ W_hh, const float* __restrict__ b_hh,
    float* __restrict__ h0_all, float* __restrict__ h1_all,
    unsigned* __restrict__ flags, float* __restrict__ xs)
{
    const int tid  = threadIdx.x;
    const int lane = tid & 63;
    const int wv   = tid >> 6;
    const int p = ((lane&1)<<5)|((lane&2)<<3)|((lane&4)<<1)
                | ((lane&8)>>1)|((lane&16)>>3)|((lane&32)>>5);  // bitrev6
    const int b_own = p >> 3, j_own = p & 7;

    unsigned* fl1 = flags;
    unsigned* fl2 = flags + 64;

    float4 wr[8][2];
    float a[64];

    if (blk < 64) {                            // ---- layer 1 ----
        const int g = blk >> 4, jb = blk & 15;
        const int bt = wv & 1, jt = wv >> 1;
        const size_t win = (size_t)(g << 4) * HID;
#pragma unroll
        for (int jj = 0; jj < 8; ++jj) {
            const float* wp = W_hh0 + (size_t)(jb*32 + jt*8 + jj) * HID;
            wr[jj][0] = *(const float4*)(wp + lane*4);
            wr[jj][1] = *(const float4*)(wp + 256 + lane*4);
        }
        const unsigned* grp = fl1 + (g << 4);
        unsigned* myf = fl1 + (g << 4) + jb;
        const int bg = (g << 4) + (bt << 3) + b_own;
        const int jg = jb*32 + jt*8 + j_own;

        for (unsigned t = 1; t <= SEQ; ++t) {
            float pf = pre0[(size_t)(t-1)*BH + (size_t)bg*HID + jg];
            for (;;) {
                unsigned v = __hip_atomic_load(&grp[lane & 15], __ATOMIC_RELAXED,
                                               __HIP_MEMORY_SCOPE_AGENT);
                if (__ballot(v < (t - 1)) == 0ull) break;
            }
            __syncthreads();
            {
                const float4* src = (const float4*)(h0_all + (size_t)(t-1)*BH + win);
                float4 r0_, r1_, r2_, r3_;
                asm volatile("global_load_dwordx4 %0, %1, off sc0 sc1" : "=v"(r0_) : "v"(src + tid));
                asm volatile("global_load_dwordx4 %0, %1, off sc0 sc1" : "=v"(r1_) : "v"(src + tid + 512));
                asm volatile("global_load_dwordx4 %0, %1, off sc0 sc1" : "=v"(r2_) : "v"(src + tid + 1024));
                asm volatile("global_load_dwordx4 %0, %1, off sc0 sc1" : "=v"(r3_) : "v"(src + tid + 1536));
                asm volatile("s_waitcnt vmcnt(0)" ::: "memory");
                __builtin_amdgcn_sched_barrier(0);
                float4* dst = (float4*)xs;
                dst[tid] = r0_; dst[tid+512] = r1_; dst[tid+1024] = r2_; dst[tid+1536] = r3_;
            }
            __syncthreads();
#pragma unroll
            for (int i = 0; i < 64; ++i) a[i] = 0.f;
#pragma unroll
            for (int b = 0; b < 8; ++b) {
                const int row = (bt << 3) + b;
                float4 ha = *(const float4*)&xs[row*512 + lane*4];
                float4 hb = *(const float4*)&xs[row*512 + 256 + lane*4];
#pragma unroll
                for (int jj = 0; jj < 8; ++jj) {
                    a[b*8+jj] += ha.x*wr[jj][0].x + ha.y*wr[jj][0].y
                               + ha.z*wr[jj][0].z + ha.w*wr[jj][0].w
                               + hb.x*wr[jj][1].x + hb.y*wr[jj][1].y
                               + hb.z*wr[jj][1].z + hb.w*wr[jj][1].w;
                }
            }
            BFLY(1,32) BFLY(2,16) BFLY(4,8) BFLY(8,4) BFLY(16,2) BFLY(32,1)
            float v = tanhf(a[0] + pf);
            __hip_atomic_store(&h0_all[(size_t)t*BH + (size_t)bg*HID + jg], v,
                               __ATOMIC_RELAXED, __HIP_MEMORY_SCOPE_AGENT);
            asm volatile("s_waitcnt vmcnt(0)" ::: "memory");
            __syncthreads();
            if (tid == 0) __hip_atomic_store(myf, t, __ATOMIC_RELAXED,
                                             __HIP_MEMORY_SCOPE_AGENT);
        }
    } else {                                   // ---- layer 2 ----
        const int idx = blk - 64;
        const int g = idx >> 5, jb = idx & 31;
        const int bt = wv & 1, jt = (wv >> 1) & 1, kt = wv >> 2;
        const size_t win = (size_t)(g << 4) * HID;
        const float* Wmat = kt ? W_hh : W_in;
#pragma unroll
        for (int jj = 0; jj < 8; ++jj) {
            const float* wp = Wmat + (size_t)(jb*16 + jt*8 + jj) * HID;
            wr[jj][0] = *(const float4*)(wp + lane*4);
            wr[jj][1] = *(const float4*)(wp + 256 + lane*4);
        }
        const unsigned* grpA = fl1 + (g << 4);
        const unsigned* grpB = fl2 + (g << 5);
        unsigned* myf = fl2 + (g << 5) + jb;
        const int bg = (g << 4) + (bt << 3) + b_own;
        const int jg = jb*16 + jt*8 + j_own;
        const float bias = b_in[jg] + b_hh[jg];
        const int scx = (wv & 3) * 64 + lane;

        for (unsigned t = 1; t <= SEQ; ++t) {
            for (;;) {
                unsigned v1 = __hip_atomic_load(&grpA[lane & 15], __ATOMIC_RELAXED,
                                                __HIP_MEMORY_SCOPE_AGENT);
                unsigned v2 = __hip_atomic_load(&grpB[lane & 31], __ATOMIC_RELAXED,
                                                __HIP_MEMORY_SCOPE_AGENT);
                if (__ballot(v1 < t) == 0ull && __ballot(v2 < (t - 1)) == 0ull) break;
            }
            __syncthreads();
            {
                const int q = tid & 255;
                const float4* src = (tid < 256)
                    ? (const float4*)(h0_all + (size_t)t*BH + win)
                    : (const float4*)(h1_all + (size_t)(t-1)*BH + win);
                float4 rr[8];
#pragma unroll
                for (int i = 0; i < 8; ++i)
                    asm volatile("global_load_dwordx4 %0, %1, off sc0 sc1"
                                 : "=v"(rr[i]) : "v"(src + q + i*256));
                asm volatile("s_waitcnt vmcnt(0)" ::: "memory");
                __builtin_amdgcn_sched_barrier(0);
                float4* dst = (float4*)(xs + ((tid < 256) ? 0 : 8192));
#pragma unroll
                for (int i = 0; i < 8; ++i) dst[q + i*256] = rr[i];
            }
            __syncthreads();
#pragma unroll
            for (int i = 0; i < 64; ++i) a[i] = 0.f;
            const float* xsrc = xs + (kt ? 8192 : 0);
#pragma unroll
            for (int b = 0; b < 8; ++b) {
                const int row = (bt << 3) + b;
                float4 ha = *(const float4*)&xsrc[row*512 + lane*4];
                float4 hb = *(const float4*)&xsrc[row*512 + 256 + lane*4];
#pragma unroll
                for (int jj = 0; jj < 8; ++jj) {
                    a[b*8+jj] += ha.x*wr[jj][0].x + ha.y*wr[jj][0].y
                               + ha.z*wr[jj][0].z + ha.w*wr[jj][0].w
                               + hb.x*wr[jj][1].x + hb.y*wr[jj][1].y
                               + hb.z*wr[jj][1].z + hb.w*wr[jj][1].w;
                }
            }
            BFLY(1,32) BFLY(2,16) BFLY(4,8) BFLY(8,4) BFLY(16,2) BFLY(32,1)
            __syncthreads();
            if (kt) xs[scx] = a[0];
            __syncthreads();
            if (!kt) {
                float v = tanhf(a[0] + xs[scx] + bias);
                __hip_atomic_store(&h1_all[(size_t)t*BH + (size_t)bg*HID + jg], v,
                                   __ATOMIC_RELAXED, __HIP_MEMORY_SCOPE_AGENT);
            }
            asm volatile("s_waitcnt vmcnt(0)" ::: "memory");
            __syncthreads();
            if (tid == 0) __hip_atomic_store(myf, t, __ATOMIC_RELAXED,
                                             __HIP_MEMORY_SCOPE_AGENT);
        }
    }
}

// Standalone v4 (fallback path)
__global__ __launch_bounds__(512) void recurrence_k(
    const float* __restrict__ pre0, const float* __restrict__ W_hh0,
    const float* __restrict__ W_in, const float* __restrict__ b_in,
    const float* __restrict__ W_hh, const float* __restrict__ b_hh,
    float* __restrict__ h0_all, float* __restrict__ h1_all,
    unsigned* __restrict__ flags)
{
    __shared__ float xs[16384];
    recurrence_body(blockIdx.x, pre0, W_hh0, W_in, b_in, W_hh, b_hh,
                    h0_all, h1_all, flags, xs);
}

// ---------------- fused with XCD-partitioned work queues ----------------
// Round-15 lesson: logits workers sharing L2 with recurrence blocks evict the
// recurrence's weight stream (857 -> 1400us). Per-XCD L2s are NOT shared, so
// partition by REAL XCD id (s_getreg hwreg(20) = HW_REG_XCC_ID, HW-verified):
// xcc<4 blocks prefer the 192 recurrence tasks, xcc>=4 prefer the 200 logits
// tasks, with cross-overflow fallback (provably all tasks claimed for any
// block->XCD distribution). Worst case (mapping useless) = round-15 behavior.
__global__ __launch_bounds__(512, 2) void rec_logitsq_k(
    const float* __restrict__ pre0, const float* __restrict__ W_hh0,
    const float* __restrict__ W_in, const float* __restrict__ b_in,
    const float* __restrict__ W_hh, const float* __restrict__ b_hh,
    float* __restrict__ h0_all, float* __restrict__ h1_all,
    unsigned* __restrict__ flags,
    const unsigned short* __restrict__ wy_hi, const float* __restrict__ by,
    float* __restrict__ Cout)
{
    __shared__ float xs[16384];   // 64 KB (recurrence staging / logits A-tile)
    __shared__ int s_task;

    if (threadIdx.x == 0) {
        unsigned xcc;
        asm volatile("s_getreg_b32 %0, hwreg(20, 0, 4)" : "=s"(xcc));
        unsigned* qr = flags + 192;   // recurrence task counter
        unsigned* qw = flags + 193;   // worker task counter
        int task = -1;
        if (xcc < 4u) {
            unsigned r = atomicAdd(qr, 1u);
            if (r < N_REC) task = (int)r;
            else {
                unsigned w = atomicAdd(qw, 1u);
                if (w < N_WORK) task = 1000 + (int)w;
            }
        } else {
            unsigned w = atomicAdd(qw, 1u);
            if (w < N_WORK) task = 1000 + (int)w;
            else {
                unsigned r = atomicAdd(qr, 1u);
                if (r < N_REC) task = (int)r;
            }
        }
        s_task = task;
    }
    __syncthreads();
    const int task = s_task;
    if (task < 0) return;

    if (task < 1000) {
        recurrence_body(task, pre0, W_hh0, W_in, b_in, W_hh, b_hh,
                        h0_all, h1_all, flags, xs);
        return;
    }

    // ---- logits worker (wid 0..199): own (timestep t, col-tile range) ----
    const int tid  = threadIdx.x;
    const int lane = tid & 63;
    const int wid = task - 1000;
    int t, ts, tc;
    if (wid < 104)      { t = wid + 1; ts = 0; tc = 79; }
    else if (wid < 136) { int q = wid - 104; t = 105 + (q >> 1); ts = (q & 1) * 40; tc = (q & 1) ? 39 : 40; }
    else                { int q = wid - 136; t = 121 + (q >> 3); int h = q & 7; ts = h * 10; tc = (h == 7) ? 9 : 10; }

    // gate: h1[t] fully published (all 128 fl2 flags >= t); gentle poll
    const unsigned* fl2p = flags + 64;
    if (tid < 64) {
        for (;;) {
            unsigned v1 = __hip_atomic_load(&fl2p[lane], __ATOMIC_RELAXED,
                                            __HIP_MEMORY_SCOPE_AGENT);
            unsigned v2 = __hip_atomic_load(&fl2p[lane + 64], __ATOMIC_RELAXED,
                                            __HIP_MEMORY_SCOPE_AGENT);
            if (__ballot(v1 < (unsigned)t) == 0ull &&
                __ballot(v2 < (unsigned)t) == 0ull) break;
            __builtin_amdgcn_s_sleep(16);
        }
    }
    __syncthreads();

    // stage A = h1[t] (64 rows x 512) -> bf16 -> LDS, 16B-granule XOR swizzle
    unsigned short* sA = (unsigned short*)xs;
    {
        const float4* src = (const float4*)(h1_all + (size_t)t * BH);
#pragma unroll
        for (int r = 0; r < 2; ++r) {
            float4 f[8];
#pragma unroll
            for (int i = 0; i < 4; ++i) {
                const float4* p0 = src + 2 * (tid + (r * 4 + i) * 512);
                asm volatile("global_load_dwordx4 %0, %1, off sc0 sc1" : "=v"(f[2*i])   : "v"(p0));
                asm volatile("global_load_dwordx4 %0, %1, off sc0 sc1" : "=v"(f[2*i+1]) : "v"(p0 + 1));
            }
            asm volatile("s_waitcnt vmcnt(0)" ::: "memory");
            __builtin_amdgcn_sched_barrier(0);
#pragma unroll
            for (int i = 0; i < 4; ++i) {
                int c = tid + (r * 4 + i) * 512;       // 16B-granule id 0..4095
                int row = c >> 6, kc = c & 63;
                float v[8] = {f[2*i].x, f[2*i].y, f[2*i].z, f[2*i].w,
                              f[2*i+1].x, f[2*i+1].y, f[2*i+1].z, f[2*i+1].w};
                unsigned hh[8];
#pragma unroll
                for (int q2 = 0; q2 < 8; ++q2) hh[q2] = bf16_rne(v[q2]);
                uint4 ph = {hh[0]|(hh[1]<<16), hh[2]|(hh[3]<<16),
                            hh[4]|(hh[5]<<16), hh[6]|(hh[7]<<16)};
                int byte = (kc * 16) ^ ((row & 7) << 4);
                *(uint4*)((char*)sA + row * 1024 + byte) = ph;
            }
        }
    }
    __syncthreads();

    // col-tiles: C tile 64 x 128; wave w owns n-subtile w (16 cols), all 4 m.
    const int w8 = tid >> 6;
    const int l15 = lane & 15, l4 = lane >> 4;
    for (int ct = ts; ct < ts + tc; ++ct) {
        const int gcol = ct * 128 + w8 * 16 + l15;
        const bool ok = gcol < VOC;
        const unsigned short* bp = wy_hi + (size_t)(ok ? gcol : 0) * 512 + l4 * 8;
        f32x4 acc[4];
#pragma unroll
        for (int mi = 0; mi < 4; ++mi) acc[mi] = (f32x4){0.f, 0.f, 0.f, 0.f};
#pragma unroll
        for (int kk = 0; kk < 16; ++kk) {
            bf16x8 fB = *(const bf16x8*)(bp + kk * 32);
#pragma unroll
            for (int mi = 0; mi < 4; ++mi) {
                int row = mi * 16 + l15;
                int byte = (kk * 64 + l4 * 16) ^ ((row & 7) << 4);
                bf16x8 fA = *(const bf16x8*)((char*)sA + row * 1024 + byte);
                acc[mi] = __builtin_amdgcn_mfma_f32_16x16x32_bf16(fA, fB, acc[mi], 0, 0, 0);
            }
        }
        if (ok) {
            float bias = by[gcol];
#pragma unroll
            for (int mi = 0; mi < 4; ++mi) {
                int grow = (t - 1) * 64 + mi * 16 + l4 * 4;
#pragma unroll
                for (int r2 = 0; r2 < 4; ++r2)
                    Cout[(size_t)(grow + r2) * VOC + gcol] = acc[mi][r2] + bias;
            }
        }
    }
}

__global__ __launch_bounds__(256) void copy_out_k(const float* __restrict__ h0_all,
                                                  const float* __restrict__ h1_all,
                                                  float* __restrict__ out_hidden) {
    int g = blockIdx.x * 256 + threadIdx.x;
    if (g < BH)            out_hidden[g] = h0_all[(size_t)SEQ * BH + g];
    else if (g < 2 * BH)   out_hidden[g] = h1_all[(size_t)SEQ * BH + (g - BH)];
}

// ---------------- bf16 weight pre-split + serial MFMA GEMMs ----------------

__global__ __launch_bounds__(256) void split_hi_k(const float* __restrict__ src,
                                                  unsigned short* __restrict__ hi,
                                                  int n4) {
    int i = blockIdx.x * 256 + threadIdx.x;
    if (i >= n4) return;
    float4 v = ((const float4*)src)[i];
    ushort4 h4;
    h4.x = (unsigned short)bf16_rne(v.x); h4.y = (unsigned short)bf16_rne(v.y);
    h4.z = (unsigned short)bf16_rne(v.z); h4.w = (unsigned short)bf16_rne(v.w);
    ((ushort4*)hi)[i] = h4;
}

// 2-pass (A split hi/lo in-register): used for pre0 (feeds the recurrence).
__global__ __launch_bounds__(256) void gemm_mfma2f_k(
    const float* __restrict__ Ag, const int* __restrict__ tok,
    const unsigned short* __restrict__ Bhg,
    const float* __restrict__ bias0, const float* __restrict__ bias1,
    float* __restrict__ C, int N, int ldc)
{
    __shared__ __align__(16) unsigned short sAh[128*64];
    __shared__ __align__(16) unsigned short sAl[128*64];
    __shared__ __align__(16) unsigned short sBh[128*64];

    const int tid = threadIdx.x;
    const int flat = blockIdx.y * gridDim.x + blockIdx.x;
    const int cpx  = (gridDim.x * gridDim.y) >> 3;
    const int w    = (flat & 7) * cpx + (flat >> 3);
    const int r0 = (w & 63) * 128, c0 = (w >> 6) * 128;

    const int lane = tid & 63, wvv = tid >> 6;
    const int mh = wvv >> 1, nh = wvv & 1;

    f32x4 acc[4][4];
#pragma unroll
    for (int i = 0; i < 4; ++i)
#pragma unroll
        for (int j = 0; j < 4; ++j) acc[i][j] = (f32x4){0.f, 0.f, 0.f, 0.f};

    const int srow = tid >> 1, shalf = tid & 1;
    const size_t arow = tok ? (size_t)tok[r0 + srow] : (size_t)(r0 + srow);
    const size_t abase = arow * 512 + (size_t)shalf * 32;
    const int brow = c0 + srow;
    const bool bok = brow < N;
    const size_t bbase = (size_t)(bok ? brow : 0) * 512 + shalf * 32;
    const int woff = srow * 64;
    const int swz = srow & 7;

    float4 fa[4][2];
    uint4 vbh[4];
#pragma unroll
    for (int g = 0; g < 4; ++g) {
        fa[g][0] = *(const float4*)(Ag + abase + g*8);
        fa[g][1] = *(const float4*)(Ag + abase + g*8 + 4);
        vbh[g]   = bok ? *(const uint4*)(Bhg + bbase + g*8) : (uint4){0,0,0,0};
    }

    for (int k0 = 0; k0 < 512; k0 += 64) {
        __syncthreads();
#pragma unroll
        for (int g = 0; g < 4; ++g) {
            float f[8] = {fa[g][0].x, fa[g][0].y, fa[g][0].z, fa[g][0].w,
                          fa[g][1].x, fa[g][1].y, fa[g][1].z, fa[g][1].w};
            unsigned hh[8], ll[8];
#pragma unroll
            for (int q = 0; q < 8; ++q) {
                hh[q] = bf16_rne(f[q]);
                ll[q] = bf16_rne(f[q] - __uint_as_float(hh[q] << 16));
            }
            uint4 ph = { hh[0] | (hh[1]<<16), hh[2] | (hh[3]<<16),
                         hh[4] | (hh[5]<<16), hh[6] | (hh[7]<<16) };
            uint4 pl = { ll[0] | (ll[1]<<16), ll[2] | (ll[3]<<16),
                         ll[4] | (ll[5]<<16), ll[6] | (ll[7]<<16) };
            int off = woff + (((shalf*4 + g) ^ swz) * 8);
            *(uint4*)&sAh[off] = ph;
            *(uint4*)&sAl[off] = pl;
            *(uint4*)&sBh[off] = vbh[g];
        }
        __syncthreads();
        if (k0 < 448) {
            const int kn = k0 + 64;
#pragma unroll
            for (int g = 0; g < 4; ++g) {
                fa[g][0] = *(const float4*)(Ag + abase + kn + g*8);
                fa[g][1] = *(const float4*)(Ag + abase + kn + g*8 + 4);
                vbh[g]   = bok ? *(const uint4*)(Bhg + bbase + kn + g*8) : (uint4){0,0,0,0};
            }
        }
#pragma unroll
        for (int c = 0; c < 2; ++c) {
            const int ks = ((c*4 + (lane >> 4)) ^ (lane & 7)) * 8;
            bf16x8 fAh[4], fAl[4], fBh[4];
#pragma unroll
            for (int mi = 0; mi < 4; ++mi) {
                int ro = (mh*64 + mi*16 + (lane & 15)) * 64;
                fAh[mi] = *(const bf16x8*)&sAh[ro + ks];
                fAl[mi] = *(const bf16x8*)&sAl[ro + ks];
            }
#pragma unroll
            for (int ni = 0; ni < 4; ++ni) {
                int ro = (nh*64 + ni*16 + (lane & 15)) * 64;
                fBh[ni] = *(const bf16x8*)&sBh[ro + ks];
            }
#pragma unroll
            for (int mi = 0; mi < 4; ++mi)
#pragma unroll
                for (int ni = 0; ni < 4; ++ni) {
                    acc[mi][ni] = __builtin_amdgcn_mfma_f32_16x16x32_bf16(
                        fAh[mi], fBh[ni], acc[mi][ni], 0, 0, 0);
                    acc[mi][ni] = __builtin_amdgcn_mfma_f32_16x16x32_bf16(
                        fAl[mi], fBh[ni], acc[mi][ni], 0, 0, 0);
                }
        }
    }

#pragma unroll
    for (int ni = 0; ni < 4; ++ni) {
        int gcol = c0 + nh*64 + ni*16 + (lane & 15);
        bool ok = gcol < N;
        float bias = 0.f;
        if (ok) {
            if (bias0) bias += bias0[gcol];
            if (bias1) bias += bias1[gcol];
        }
#pragma unroll
        for (int mi = 0; mi < 4; ++mi) {
            int grow = r0 + mh*64 + mi*16 + ((lane >> 4) << 2);
#pragma unroll
            for (int r = 0; r < 4; ++r)
                if (ok) C[(size_t)(grow + r) * ldc + gcol] = acc[mi][ni][r] + bias;
        }
    }
}

// 1-pass serial logits GEMM (fallback if fused coop launch fails).
__global__ __launch_bounds__(256) void gemm_mfma1f_k(
    const float* __restrict__ Ag,
    const unsigned short* __restrict__ Bhg,
    const float* __restrict__ bias0,
    float* __restrict__ C, int N, int ldc)
{
    __shared__ __align__(16) unsigned short sAh[128*64];
    __shared__ __align__(16) unsigned short sBh[128*64];

    const int tid = threadIdx.x;
    const int flat = blockIdx.y * gridDim.x + blockIdx.x;
    const int cpx  = (gridDim.x * gridDim.y) >> 3;
    const int w    = (flat & 7) * cpx + (flat >> 3);
    const int r0 = (w & 63) * 128, c0 = (w >> 6) * 128;

    const int lane = tid & 63, wvv = tid >> 6;
    const int mh = wvv >> 1, nh = wvv & 1;

    f32x4 acc[4][4];
#pragma unroll
    for (int i = 0; i < 4; ++i)
#pragma unroll
        for (int j = 0; j < 4; ++j) acc[i][j] = (f32x4){0.f, 0.f, 0.f, 0.f};

    const int srow = tid >> 1, shalf = tid & 1;
    const size_t abase = (size_t)(r0 + srow) * 512 + (size_t)shalf * 32;
    const int brow = c0 + srow;
    const bool bok = brow < N;
    const size_t bbase = (size_t)(bok ? brow : 0) * 512 + shalf * 32;
    const int woff = srow * 64;
    const int swz = srow & 7;

    float4 fa[4][2];
    uint4 vbh[4];
#pragma unroll
    for (int g = 0; g < 4; ++g) {
        fa[g][0] = *(const float4*)(Ag + abase + g*8);
        fa[g][1] = *(const float4*)(Ag + abase + g*8 + 4);
        vbh[g]   = bok ? *(const uint4*)(Bhg + bbase + g*8) : (uint4){0,0,0,0};
    }

    for (int k0 = 0; k0 < 512; k0 += 64) {
        __syncthreads();
#pragma unroll
        for (int g = 0; g < 4; ++g) {
            float f[8] = {fa[g][0].x, fa[g][0].y, fa[g][0].z, fa[g][0].w,
                          fa[g][1].x, fa[g][1].y, fa[g][1].z, fa[g][1].w};
            unsigned hh[8];
#pragma unroll
            for (int q = 0; q < 8; ++q) hh[q] = bf16_rne(f[q]);
            uint4 ph = { hh[0] | (hh[1]<<16), hh[2] | (hh[3]<<16),
                         hh[4] | (hh[5]<<16), hh[6] | (hh[7]<<16) };
            int off = woff + (((shalf*4 + g) ^ swz) * 8);
            *(uint4*)&sAh[off] = ph;
            *(uint4*)&sBh[off] = vbh[g];
        }
        __syncthreads();
        if (k0 < 448) {
            const int kn = k0 + 64;
#pragma unroll
            for (int g = 0; g < 4; ++g) {
                fa[g][0] = *(const float4*)(Ag + abase + kn + g*8);
                fa[g][1] = *(const float4*)(Ag + abase + kn + g*8 + 4);
                vbh[g]   = bok ? *(const uint4*)(Bhg + bbase + kn + g*8) : (uint4){0,0,0,0};
            }
        }
#pragma unroll
        for (int c = 0; c < 2; ++c) {
            const int ks = ((c*4 + (lane >> 4)) ^ (lane & 7)) * 8;
            bf16x8 fAh[4], fBh[4];
#pragma unroll
            for (int mi = 0; mi < 4; ++mi) {
                int ro = (mh*64 + mi*16 + (lane & 15)) * 64;
                fAh[mi] = *(const bf16x8*)&sAh[ro + ks];
            }
#pragma unroll
            for (int ni = 0; ni < 4; ++ni) {
                int ro = (nh*64 + ni*16 + (lane & 15)) * 64;
                fBh[ni] = *(const bf16x8*)&sBh[ro + ks];
            }
#pragma unroll
            for (int mi = 0; mi < 4; ++mi)
#pragma unroll
                for (int ni = 0; ni < 4; ++ni)
                    acc[mi][ni] = __builtin_amdgcn_mfma_f32_16x16x32_bf16(
                        fAh[mi], fBh[ni], acc[mi][ni], 0, 0, 0);
        }
    }

#pragma unroll
    for (int ni = 0; ni < 4; ++ni) {
        int gcol = c0 + nh*64 + ni*16 + (lane & 15);
        bool ok = gcol < N;
        float bias = ok ? bias0[gcol] : 0.f;
#pragma unroll
        for (int mi = 0; mi < 4; ++mi) {
            int grow = r0 + mh*64 + mi*16 + ((lane >> 4) << 2);
#pragma unroll
            for (int r = 0; r < 4; ++r)
                if (ok) C[(size_t)(grow + r) * ldc + gcol] = acc[mi][ni][r] + bias;
        }
    }
}

extern "C" void kernel_launch(void* const* d_in, const int* in_sizes, int n_in,
                              void* d_out, int out_size, void* d_ws, size_t ws_size,
                              hipStream_t stream) {
    const int*   inputs = (const int*)d_in[0];
    const float* hidden = (const float*)d_in[1];
    const float* emb    = (const float*)d_in[2];
    const float* W_ih0  = (const float*)d_in[3];
    const float* b_ih0  = (const float*)d_in[4];
    const float* W_hh0  = (const float*)d_in[5];
    const float* b_hh0  = (const float*)d_in[6];
    const float* W_in   = (const float*)d_in[7];
    const float* b_in   = (const float*)d_in[8];
    const float* W_hh   = (const float*)d_in[9];
    const float* b_hh   = (const float*)d_in[10];
    const float* Wy     = (const float*)d_in[11];
    const float* by     = (const float*)d_in[12];
    float* out = (float*)d_out;

    float* ws     = (float*)d_ws;
    float* pre0   = ws + PRE0_OFF;
    float* h0_all = ws + H0_OFF;
    float* h1_all = ws + H1_OFF;
    unsigned* flags = (unsigned*)(ws + FLAGS_OFF);
    float* out_hidden = out + LOGITS_N;
    const bool big_ws = (ws_size >= WS_NEED_FLOATS * 4ull);

    unsigned short* wy_hi   = (unsigned short*)(ws + CONV_OFF);
    unsigned short* wih0_hi = wy_hi + (size_t)VOC * HID;

    // 1) initial hidden state -> slot 0; zero flags + queue counters
    init_state_k<<<dim3((BH + 255) / 256), dim3(256), 0, stream>>>(hidden, h0_all, h1_all, flags);

    const float* pre0_c = pre0;
    if (big_ws) {
        // 2) weight pre-splits + pre0 (2-pass MFMA)
        split_hi_k<<<dim3(1024), dim3(256), 0, stream>>>(W_ih0, wih0_hi, HID*EMBD/4);
        split_hi_k<<<dim3(5000), dim3(256), 0, stream>>>(Wy, wy_hi, VOC*HID/4);
        gemm_mfma2f_k<<<dim3(64, 4), dim3(256), 0, stream>>>(
            emb, inputs, wih0_hi, b_ih0, b_hh0, pre0, HID, HID);

        // 3) fused recurrence + XCD-partitioned logits workers (400 blocks)
        void* kargsF[] = { (void*)&pre0_c, (void*)&W_hh0, (void*)&W_in, (void*)&b_in,
                           (void*)&W_hh, (void*)&b_hh, (void*)&h0_all, (void*)&h1_all,
                           (void*)&flags, (void*)&wy_hi, (void*)&by, (void*)&out };
        hipError_t e = hipLaunchCooperativeKernel((const void*)rec_logitsq_k,
                                                  dim3(400), dim3(512), kargsF, 0, stream);
        if (e != hipSuccess) {
            (void)hipGetLastError();   // clear error state
            // fallback: proven serial path (round-12 behavior)
            void* kargs[] = { (void*)&pre0_c, (void*)&W_hh0, (void*)&W_in, (void*)&b_in,
                              (void*)&W_hh, (void*)&b_hh, (void*)&h0_all, (void*)&h1_all,
                              (void*)&flags };
            hipLaunchCooperativeKernel((const void*)recurrence_k, dim3(192), dim3(512),
                                       kargs, 0, stream);
            gemm_mfma1f_k<<<dim3(64, 79), dim3(256), 0, stream>>>(
                h1_all + BH, wy_hi, by, out, VOC, VOC);
        }
    } else {
        // small-ws fallback: fp32 GEMMs + serial recurrence
        gemm_nt_k<<<dim3(64, 4), dim3(256), 0, stream>>>(
            emb, inputs, W_ih0, b_ih0, b_hh0, pre0, HID, EMBD, HID);
        void* kargs[] = { (void*)&pre0_c, (void*)&W_hh0, (void*)&W_in, (void*)&b_in,
                          (void*)&W_hh, (void*)&b_hh, (void*)&h0_all, (void*)&h1_all,
                          (void*)&flags };
        hipLaunchCooperativeKernel((const void*)recurrence_k, dim3(192), dim3(512),
                                   kargs, 0, stream);
        gemm_nt_k<<<dim3(64, 79), dim3(256), 0, stream>>>(
            h1_all + BH, nullptr, Wy, nullptr, by, out, VOC, HID, VOC);
    }

    // 4) final hidden -> d_out tail
    copy_out_k<<<dim3(256), dim3(256), 0, stream>>>(h0_all, h1_all, out_hidden);
}

// Round 17
// 1121.737 us; speedup vs baseline: 1.7554x; 1.7554x over previous
//
#include <hip/hip_runtime.h>
#include <hip/hip_bf16.h>

#define SEQ 128
#define BAT 64
#define VOC 10000
#define EMBD 512
#define HID 512
#define BH (BAT*HID)                  // 32768
// workspace layout (floats)
#define PRE0_OFF 0
#define H0_OFF   ((size_t)SEQ*BH)                 // pre0: 128*BH
#define H1_OFF   (H0_OFF + (size_t)(SEQ+1)*BH)
#define FLAGS_OFF (H1_OFF + (size_t)(SEQ+1)*BH)   // 256 uints: fl1[0..63], fl2[64..191], q[192..195]
#define CONV_OFF (FLAGS_OFF + 256)                // bf16 weight arrays
#define LOGITS_N ((size_t)SEQ*BAT*VOC)            // 81,920,000 (in d_out)
// conv region (ushorts): wy_hi 5,120,000 + wih0_hi 262,144
#define CONV_USHORTS 5382144ull
#define WS_NEED_FLOATS (CONV_OFF + CONV_USHORTS/2)

typedef __attribute__((ext_vector_type(8))) __bf16 bf16x8;
typedef __attribute__((ext_vector_type(4))) float f32x4;

__global__ __launch_bounds__(256) void init_state_k(const float* __restrict__ hidden,
                                                    float* __restrict__ h0_0,
                                                    float* __restrict__ h1_0,
                                                    unsigned* __restrict__ flags) {
    int i = blockIdx.x * 256 + threadIdx.x;
    if (i < 256) flags[i] = 0u;   // includes 4 group-queue counters at [192..195]
    if (i < BH) { h0_0[i] = hidden[i]; h1_0[i] = hidden[BH + i]; }
}

// fp32 GEMM fallback (only if ws too small for bf16-split path).
__global__ __launch_bounds__(256) void gemm_nt_k(
    const float* __restrict__ A, const int* __restrict__ tok,
    const float* __restrict__ Bm,
    const float* __restrict__ bias0, const float* __restrict__ bias1,
    float* __restrict__ C, int N, int K, int ldc)
{
    __shared__ float As[32][132];
    __shared__ float Bs[32][132];
    __shared__ int toks[128];

    const int tid = threadIdx.x;
    const int r0 = blockIdx.x * 128;
    const int c0 = blockIdx.y * 128;

    if (tok != nullptr && tid < 128) toks[tid] = tok[r0 + tid];
    __syncthreads();

    const int tn = tid & 15;
    const int tm = tid >> 4;
    const int m0 = tm * 8, n0 = tn * 8;

    float acc[8][8];
#pragma unroll
    for (int i = 0; i < 8; ++i)
#pragma unroll
        for (int j = 0; j < 8; ++j) acc[i][j] = 0.f;

    for (int k0 = 0; k0 < K; k0 += 32) {
#pragma unroll
        for (int p = 0; p < 4; ++p) {
            int idx = p * 256 + tid;
            int row = idx >> 3;
            int kq  = (idx & 7) << 2;
            size_t arow = tok ? (size_t)toks[row] : (size_t)(r0 + row);
            float4 a = *(const float4*)(A + arow * (size_t)K + k0 + kq);
            As[kq+0][row] = a.x; As[kq+1][row] = a.y;
            As[kq+2][row] = a.z; As[kq+3][row] = a.w;
            int gc = c0 + row;
            float4 b = make_float4(0.f, 0.f, 0.f, 0.f);
            if (gc < N) b = *(const float4*)(Bm + (size_t)gc * K + k0 + kq);
            Bs[kq+0][row] = b.x; Bs[kq+1][row] = b.y;
            Bs[kq+2][row] = b.z; Bs[kq+3][row] = b.w;
        }
        __syncthreads();
#pragma unroll 8
        for (int k = 0; k < 32; ++k) {
            float4 a0 = *(const float4*)&As[k][m0];
            float4 a1 = *(const float4*)&As[k][m0 + 4];
            float4 b0 = *(const float4*)&Bs[k][n0];
            float4 b1 = *(const float4*)&Bs[k][n0 + 4];
            float am[8] = {a0.x,a0.y,a0.z,a0.w,a1.x,a1.y,a1.z,a1.w};
            float bn[8] = {b0.x,b0.y,b0.z,b0.w,b1.x,b1.y,b1.z,b1.w};
#pragma unroll
            for (int i = 0; i < 8; ++i)
#pragma unroll
                for (int j = 0; j < 8; ++j) acc[i][j] += am[i] * bn[j];
        }
        __syncthreads();
    }

    const bool full = (c0 + 128 <= N);
#pragma unroll
    for (int i = 0; i < 8; ++i) {
        size_t r = (size_t)(r0 + m0 + i);
        float* crow = C + r * (size_t)ldc;
#pragma unroll
        for (int j = 0; j < 8; ++j) {
            int c = c0 + n0 + j;
            if (full || c < N) {
                float v = acc[i][j];
                if (bias0) v += bias0[c];
                if (bias1) v += bias1[c];
                crow[c] = v;
            }
        }
    }
}

#define BFLY(S, N)                                                     \
    {                                                                  \
        _Pragma("unroll")                                              \
        for (int i = 0; i < N; ++i) {                                  \
            float lo_ = a[i], hi_ = a[i + N];                          \
            float send_ = (lane & S) ? lo_ : hi_;                      \
            float recv_ = __shfl_xor(send_, S);                       \
            a[i] = ((lane & S) ? hi_ : lo_) + recv_;                   \
        }                                                              \
    }

__device__ __forceinline__ unsigned bf16_rne(float x) {
    unsigned u = __float_as_uint(x);
    unsigned r = u + 0x7fffu + ((u >> 16) & 1u);
    return r >> 16;
}

// ---- v4 recurrence body, task id 0..191. Stage loads use sc0 ONLY
// (L1-bypass, L2-ELIGIBLE): a slot's lines are never read pre-flag by any
// agent, so no stale local-L2 copy can exist; an L2 miss falls through to L3
// (fresh, since producer stores are sc1 write-through). With same-XCD group
// placement (v9 kernel below) the staged reads can hit the local L2. ----
__device__ __forceinline__ void recurrence_body(
    int blk,
    const float* __restrict__ pre0, const float* __restrict__ W_hh0,
    const float* __restrict__ W_in, const float* __restrict__ b_in,
    const float* __restrict__ W_hh, const float* __restrict__ b_hh,
    float* __restrict__ h0_all, float* __restrict__ h1_all,
    unsigned* __restrict__ flags, float* __restrict__ xs)
{
    const int tid  = threadIdx.x;
    const int lane = tid & 63;
    const int wv   = tid >> 6;
    const int p = ((lane&1)<<5)|((lane&2)<<3)|((lane&4)<<1)
                | ((lane&8)>>1)|((lane&16)>>3)|((lane&32)>>5);  // bitrev6
    const int b_own = p >> 3, j_own = p & 7;

    unsigned* fl1 = flags;
    unsigned* fl2 = flags + 64;

    float4 wr[8][2];
    float a[64];

    if (blk < 64) {                            // ---- layer 1 ----
        const int g = blk >> 4, jb = blk & 15;
        const int bt = wv & 1, jt = wv >> 1;
        const size_t win = (size_t)(g << 4) * HID;
#pragma unroll
        for (int jj = 0; jj < 8; ++jj) {
            const float* wp = W_hh0 + (size_t)(jb*32 + jt*8 + jj) * HID;
            wr[jj][0] = *(const float4*)(wp + lane*4);
            wr[jj][1] = *(const float4*)(wp + 256 + lane*4);
        }
        const unsigned* grp = fl1 + (g << 4);
        unsigned* myf = fl1 + (g << 4) + jb;
        const int bg = (g << 4) + (bt << 3) + b_own;
        const int jg = jb*32 + jt*8 + j_own;

        for (unsigned t = 1; t <= SEQ; ++t) {
            float pf = pre0[(size_t)(t-1)*BH + (size_t)bg*HID + jg];
            for (;;) {
                unsigned v = __hip_atomic_load(&grp[lane & 15], __ATOMIC_RELAXED,
                                               __HIP_MEMORY_SCOPE_AGENT);
                if (__ballot(v < (t - 1)) == 0ull) break;
            }
            __syncthreads();
            {
                const float4* src = (const float4*)(h0_all + (size_t)(t-1)*BH + win);
                float4 r0_, r1_, r2_, r3_;
                asm volatile("global_load_dwordx4 %0, %1, off sc0" : "=v"(r0_) : "v"(src + tid));
                asm volatile("global_load_dwordx4 %0, %1, off sc0" : "=v"(r1_) : "v"(src + tid + 512));
                asm volatile("global_load_dwordx4 %0, %1, off sc0" : "=v"(r2_) : "v"(src + tid + 1024));
                asm volatile("global_load_dwordx4 %0, %1, off sc0" : "=v"(r3_) : "v"(src + tid + 1536));
                asm volatile("s_waitcnt vmcnt(0)" ::: "memory");
                __builtin_amdgcn_sched_barrier(0);
                float4* dst = (float4*)xs;
                dst[tid] = r0_; dst[tid+512] = r1_; dst[tid+1024] = r2_; dst[tid+1536] = r3_;
            }
            __syncthreads();
#pragma unroll
            for (int i = 0; i < 64; ++i) a[i] = 0.f;
#pragma unroll
            for (int b = 0; b < 8; ++b) {
                const int row = (bt << 3) + b;
                float4 ha = *(const float4*)&xs[row*512 + lane*4];
                float4 hb = *(const float4*)&xs[row*512 + 256 + lane*4];
#pragma unroll
                for (int jj = 0; jj < 8; ++jj) {
                    a[b*8+jj] += ha.x*wr[jj][0].x + ha.y*wr[jj][0].y
                               + ha.z*wr[jj][0].z + ha.w*wr[jj][0].w
                               + hb.x*wr[jj][1].x + hb.y*wr[jj][1].y
                               + hb.z*wr[jj][1].z + hb.w*wr[jj][1].w;
                }
            }
            BFLY(1,32) BFLY(2,16) BFLY(4,8) BFLY(8,4) BFLY(16,2) BFLY(32,1)
            float v = tanhf(a[0] + pf);
            __hip_atomic_store(&h0_all[(size_t)t*BH + (size_t)bg*HID + jg], v,
                               __ATOMIC_RELAXED, __HIP_MEMORY_SCOPE_AGENT);
            asm volatile("s_waitcnt vmcnt(0)" ::: "memory");
            __syncthreads();
            if (tid == 0) __hip_atomic_store(myf, t, __ATOMIC_RELAXED,
                                             __HIP_MEMORY_SCOPE_AGENT);
        }
    } else {                                   // ---- layer 2 ----
        const int idx = blk - 64;
        const int g = idx >> 5, jb = idx & 31;
        const int bt = wv & 1, jt = (wv >> 1) & 1, kt = wv >> 2;
        const size_t win = (size_t)(g << 4) * HID;
        const float* Wmat = kt ? W_hh : W_in;
#pragma unroll
        for (int jj = 0; jj < 8; ++jj) {
            const float* wp = Wmat + (size_t)(jb*16 + jt*8 + jj) * HID;
            wr[jj][0] = *(const float4*)(wp + lane*4);
            wr[jj][1] = *(const float4*)(wp + 256 + lane*4);
        }
        const unsigned* grpA = fl1 + (g << 4);
        const unsigned* grpB = fl2 + (g << 5);
        unsigned* myf = fl2 + (g << 5) + jb;
        const int bg = (g << 4) + (bt << 3) + b_own;
        const int jg = jb*16 + jt*8 + j_own;
        const float bias = b_in[jg] + b_hh[jg];
        const int scx = (wv & 3) * 64 + lane;

        for (unsigned t = 1; t <= SEQ; ++t) {
            for (;;) {
                unsigned v1 = __hip_atomic_load(&grpA[lane & 15], __ATOMIC_RELAXED,
                                                __HIP_MEMORY_SCOPE_AGENT);
                unsigned v2 = __hip_atomic_load(&grpB[lane & 31], __ATOMIC_RELAXED,
                                                __HIP_MEMORY_SCOPE_AGENT);
                if (__ballot(v1 < t) == 0ull && __ballot(v2 < (t - 1)) == 0ull) break;
            }
            __syncthreads();
            {
                const int q = tid & 255;
                const float4* src = (tid < 256)
                    ? (const float4*)(h0_all + (size_t)t*BH + win)
                    : (const float4*)(h1_all + (size_t)(t-1)*BH + win);
                float4 rr[8];
#pragma unroll
                for (int i = 0; i < 8; ++i)
                    asm volatile("global_load_dwordx4 %0, %1, off sc0"
                                 : "=v"(rr[i]) : "v"(src + q + i*256));
                asm volatile("s_waitcnt vmcnt(0)" ::: "memory");
                __builtin_amdgcn_sched_barrier(0);
                float4* dst = (float4*)(xs + ((tid < 256) ? 0 : 8192));
#pragma unroll
                for (int i = 0; i < 8; ++i) dst[q + i*256] = rr[i];
            }
            __syncthreads();
#pragma unroll
            for (int i = 0; i < 64; ++i) a[i] = 0.f;
            const float* xsrc = xs + (kt ? 8192 : 0);
#pragma unroll
            for (int b = 0; b < 8; ++b) {
                const int row = (bt << 3) + b;
                float4 ha = *(const float4*)&xsrc[row*512 + lane*4];
                float4 hb = *(const float4*)&xsrc[row*512 + 256 + lane*4];
#pragma unroll
                for (int jj = 0; jj < 8; ++jj) {
                    a[b*8+jj] += ha.x*wr[jj][0].x + ha.y*wr[jj][0].y
                               + ha.z*wr[jj][0].z + ha.w*wr[jj][0].w
                               + hb.x*wr[jj][1].x + hb.y*wr[jj][1].y
                               + hb.z*wr[jj][1].z + hb.w*wr[jj][1].w;
                }
            }
            BFLY(1,32) BFLY(2,16) BFLY(4,8) BFLY(8,4) BFLY(16,2) BFLY(32,1)
            __syncthreads();
            if (kt) xs[scx] = a[0];
            __syncthreads();
            if (!kt) {
                float v = tanhf(a[0] + xs[scx] + bias);
                __hip_atomic_store(&h1_all[(size_t)t*BH + (size_t)bg*HID + jg], v,
                                   __ATOMIC_RELAXED, __HIP_MEMORY_SCOPE_AGENT);
            }
            asm volatile("s_waitcnt vmcnt(0)" ::: "memory");
            __syncthreads();
            if (tid == 0) __hip_atomic_store(myf, t, __ATOMIC_RELAXED,
                                             __HIP_MEMORY_SCOPE_AGENT);
        }
    }
}

// Standalone v4 (fallback path; placement-free, same body)
__global__ __launch_bounds__(512) void recurrence_k(
    const float* __restrict__ pre0, const float* __restrict__ W_hh0,
    const float* __restrict__ W_in, const float* __restrict__ b_in,
    const float* __restrict__ W_hh, const float* __restrict__ b_hh,
    float* __restrict__ h0_all, float* __restrict__ h1_all,
    unsigned* __restrict__ flags)
{
    __shared__ float xs[16384];
    recurrence_body(blockIdx.x, pre0, W_hh0, W_in, b_in, W_hh, b_hh,
                    h0_all, h1_all, flags, xs);
}

// ---------------- recurrence v9: XCD-grouped placement ----------------
// Launch 384 blocks (48/XCD expected). Group g (g<4) = 48 tasks (16 L1 +
// 32 L2) whose h-window traffic is entirely intra-group. Blocks on XCD g<4
// claim group-g tasks immediately (one XCD holds a whole group -> staged h
// reads can hit the LOCAL L2 via the sc0-only loads). Blocks on XCD>=4
// sleep ~3us then sweep leftovers (liveness for any dispatch distribution;
// worst case = unplaced v4 behavior). Unclaimed blocks exit.
__global__ __launch_bounds__(512) void recurrence9_k(
    const float* __restrict__ pre0, const float* __restrict__ W_hh0,
    const float* __restrict__ W_in, const float* __restrict__ b_in,
    const float* __restrict__ W_hh, const float* __restrict__ b_hh,
    float* __restrict__ h0_all, float* __restrict__ h1_all,
    unsigned* __restrict__ flags)
{
    __shared__ float xs[16384];
    __shared__ int s_task;

    if (threadIdx.x == 0) {
        unsigned xcc;
        asm volatile("s_getreg_b32 %0, hwreg(20, 0, 4)" : "=s"(xcc));
        unsigned* q = flags + 192;    // 4 group queues
        int task = -1;
        if (xcc < 4u) {
            unsigned r = atomicAdd(&q[xcc], 1u);
            if (r < 48u) task = (r < 16u) ? (int)(xcc*16u + r)
                                          : (int)(64u + xcc*32u + (r - 16u));
        }
        if (task < 0) {
            __builtin_amdgcn_s_sleep(127);   // ~3.4us: let home-XCD blocks claim first
            for (unsigned g = 0; g < 4u && task < 0; ++g) {
                unsigned r = atomicAdd(&q[g], 1u);
                if (r < 48u) task = (r < 16u) ? (int)(g*16u + r)
                                              : (int)(64u + g*32u + (r - 16u));
            }
        }
        s_task = task;
    }
    __syncthreads();
    const int task = s_task;
    if (task < 0) return;

    recurrence_body(task, pre0, W_hh0, W_in, b_in, W_hh, b_hh,
                    h0_all, h1_all, flags, xs);
}

__global__ __launch_bounds__(256) void copy_out_k(const float* __restrict__ h0_all,
                                                  const float* __restrict__ h1_all,
                                                  float* __restrict__ out_hidden) {
    int g = blockIdx.x * 256 + threadIdx.x;
    if (g < BH)            out_hidden[g] = h0_all[(size_t)SEQ * BH + g];
    else if (g < 2 * BH)   out_hidden[g] = h1_all[(size_t)SEQ * BH + (g - BH)];
}

// ---------------- bf16 weight pre-split (merged) + MFMA GEMMs ----------------

// One launch splits BOTH Wy (hi) and W_ih0 (hi).
__global__ __launch_bounds__(256) void split2_hi_k(const float* __restrict__ wy,
                                                   const float* __restrict__ wih0,
                                                   unsigned short* __restrict__ wy_hi,
                                                   unsigned short* __restrict__ wih0_hi) {
    const int n4a = VOC*HID/4;       // 1,280,000
    const int n4b = HID*EMBD/4;      //    65,536
    int i = blockIdx.x * 256 + threadIdx.x;
    const float* src; unsigned short* dst; int idx;
    if (i < n4a)            { src = wy;   dst = wy_hi;   idx = i; }
    else if (i < n4a + n4b) { src = wih0; dst = wih0_hi; idx = i - n4a; }
    else return;
    float4 v = ((const float4*)src)[idx];
    ushort4 h4;
    h4.x = (unsigned short)bf16_rne(v.x); h4.y = (unsigned short)bf16_rne(v.y);
    h4.z = (unsigned short)bf16_rne(v.z); h4.w = (unsigned short)bf16_rne(v.w);
    ((ushort4*)dst)[idx] = h4;
}

// 2-pass (A split hi/lo in-register): used for pre0 (feeds the recurrence).
__global__ __launch_bounds__(256) void gemm_mfma2f_k(
    const float* __restrict__ Ag, const int* __restrict__ tok,
    const unsigned short* __restrict__ Bhg,
    const float* __restrict__ bias0, const float* __restrict__ bias1,
    float* __restrict__ C, int N, int ldc)
{
    __shared__ __align__(16) unsigned short sAh[128*64];
    __shared__ __align__(16) unsigned short sAl[128*64];
    __shared__ __align__(16) unsigned short sBh[128*64];

    const int tid = threadIdx.x;
    const int flat = blockIdx.y * gridDim.x + blockIdx.x;
    const int cpx  = (gridDim.x * gridDim.y) >> 3;
    const int w    = (flat & 7) * cpx + (flat >> 3);
    const int r0 = (w & 63) * 128, c0 = (w >> 6) * 128;

    const int lane = tid & 63, wvv = tid >> 6;
    const int mh = wvv >> 1, nh = wvv & 1;

    f32x4 acc[4][4];
#pragma unroll
    for (int i = 0; i < 4; ++i)
#pragma unroll
        for (int j = 0; j < 4; ++j) acc[i][j] = (f32x4){0.f, 0.f, 0.f, 0.f};

    const int srow = tid >> 1, shalf = tid & 1;
    const size_t arow = tok ? (size_t)tok[r0 + srow] : (size_t)(r0 + srow);
    const size_t abase = arow * 512 + (size_t)shalf * 32;
    const int brow = c0 + srow;
    const bool bok = brow < N;
    const size_t bbase = (size_t)(bok ? brow : 0) * 512 + shalf * 32;
    const int woff = srow * 64;
    const int swz = srow & 7;

    float4 fa[4][2];
    uint4 vbh[4];
#pragma unroll
    for (int g = 0; g < 4; ++g) {
        fa[g][0] = *(const float4*)(Ag + abase + g*8);
        fa[g][1] = *(const float4*)(Ag + abase + g*8 + 4);
        vbh[g]   = bok ? *(const uint4*)(Bhg + bbase + g*8) : (uint4){0,0,0,0};
    }

    for (int k0 = 0; k0 < 512; k0 += 64) {
        __syncthreads();
#pragma unroll
        for (int g = 0; g < 4; ++g) {
            float f[8] = {fa[g][0].x, fa[g][0].y, fa[g][0].z, fa[g][0].w,
                          fa[g][1].x, fa[g][1].y, fa[g][1].z, fa[g][1].w};
            unsigned hh[8], ll[8];
#pragma unroll
            for (int q = 0; q < 8; ++q) {
                hh[q] = bf16_rne(f[q]);
                ll[q] = bf16_rne(f[q] - __uint_as_float(hh[q] << 16));
            }
            uint4 ph = { hh[0] | (hh[1]<<16), hh[2] | (hh[3]<<16),
                         hh[4] | (hh[5]<<16), hh[6] | (hh[7]<<16) };
            uint4 pl = { ll[0] | (ll[1]<<16), ll[2] | (ll[3]<<16),
                         ll[4] | (ll[5]<<16), ll[6] | (ll[7]<<16) };
            int off = woff + (((shalf*4 + g) ^ swz) * 8);
            *(uint4*)&sAh[off] = ph;
            *(uint4*)&sAl[off] = pl;
            *(uint4*)&sBh[off] = vbh[g];
        }
        __syncthreads();
        if (k0 < 448) {
            const int kn = k0 + 64;
#pragma unroll
            for (int g = 0; g < 4; ++g) {
                fa[g][0] = *(const float4*)(Ag + abase + kn + g*8);
                fa[g][1] = *(const float4*)(Ag + abase + kn + g*8 + 4);
                vbh[g]   = bok ? *(const uint4*)(Bhg + bbase + kn + g*8) : (uint4){0,0,0,0};
            }
        }
#pragma unroll
        for (int c = 0; c < 2; ++c) {
            const int ks = ((c*4 + (lane >> 4)) ^ (lane & 7)) * 8;
            bf16x8 fAh[4], fAl[4], fBh[4];
#pragma unroll
            for (int mi = 0; mi < 4; ++mi) {
                int ro = (mh*64 + mi*16 + (lane & 15)) * 64;
                fAh[mi] = *(const bf16x8*)&sAh[ro + ks];
                fAl[mi] = *(const bf16x8*)&sAl[ro + ks];
            }
#pragma unroll
            for (int ni = 0; ni < 4; ++ni) {
                int ro = (nh*64 + ni*16 + (lane & 15)) * 64;
                fBh[ni] = *(const bf16x8*)&sBh[ro + ks];
            }
#pragma unroll
            for (int mi = 0; mi < 4; ++mi)
#pragma unroll
                for (int ni = 0; ni < 4; ++ni) {
                    acc[mi][ni] = __builtin_amdgcn_mfma_f32_16x16x32_bf16(
                        fAh[mi], fBh[ni], acc[mi][ni], 0, 0, 0);
                    acc[mi][ni] = __builtin_amdgcn_mfma_f32_16x16x32_bf16(
                        fAl[mi], fBh[ni], acc[mi][ni], 0, 0, 0);
                }
        }
    }

#pragma unroll
    for (int ni = 0; ni < 4; ++ni) {
        int gcol = c0 + nh*64 + ni*16 + (lane & 15);
        bool ok = gcol < N;
        float bias = 0.f;
        if (ok) {
            if (bias0) bias += bias0[gcol];
            if (bias1) bias += bias1[gcol];
        }
#pragma unroll
        for (int mi = 0; mi < 4; ++mi) {
            int grow = r0 + mh*64 + mi*16 + ((lane >> 4) << 2);
#pragma unroll
            for (int r = 0; r < 4; ++r)
                if (ok) C[(size_t)(grow + r) * ldc + gcol] = acc[mi][ni][r] + bias;
        }
    }
}

// 1-pass logits GEMM (serial; A fp32 -> bf16 in-register, B pre-split bf16).
__global__ __launch_bounds__(256) void gemm_mfma1f_k(
    const float* __restrict__ Ag,
    const unsigned short* __restrict__ Bhg,
    const float* __restrict__ bias0,
    float* __restrict__ C, int N, int ldc)
{
    __shared__ __align__(16) unsigned short sAh[128*64];
    __shared__ __align__(16) unsigned short sBh[128*64];

    const int tid = threadIdx.x;
    const int flat = blockIdx.y * gridDim.x + blockIdx.x;
    const int cpx  = (gridDim.x * gridDim.y) >> 3;
    const int w    = (flat & 7) * cpx + (flat >> 3);
    const int r0 = (w & 63) * 128, c0 = (w >> 6) * 128;

    const int lane = tid & 63, wvv = tid >> 6;
    const int mh = wvv >> 1, nh = wvv & 1;

    f32x4 acc[4][4];
#pragma unroll
    for (int i = 0; i < 4; ++i)
#pragma unroll
        for (int j = 0; j < 4; ++j) acc[i][j] = (f32x4){0.f, 0.f, 0.f, 0.f};

    const int srow = tid >> 1, shalf = tid & 1;
    const size_t abase = (size_t)(r0 + srow) * 512 + (size_t)shalf * 32;
    const int brow = c0 + srow;
    const bool bok = brow < N;
    const size_t bbase = (size_t)(bok ? brow : 0) * 512 + shalf * 32;
    const int woff = srow * 64;
    const int swz = srow & 7;

    float4 fa[4][2];
    uint4 vbh[4];
#pragma unroll
    for (int g = 0; g < 4; ++g) {
        fa[g][0] = *(const float4*)(Ag + abase + g*8);
        fa[g][1] = *(const float4*)(Ag + abase + g*8 + 4);
        vbh[g]   = bok ? *(const uint4*)(Bhg + bbase + g*8) : (uint4){0,0,0,0};
    }

    for (int k0 = 0; k0 < 512; k0 += 64) {
        __syncthreads();
#pragma unroll
        for (int g = 0; g < 4; ++g) {
            float f[8] = {fa[g][0].x, fa[g][0].y, fa[g][0].z, fa[g][0].w,
                          fa[g][1].x, fa[g][1].y, fa[g][1].z, fa[g][1].w};
            unsigned hh[8];
#pragma unroll
            for (int q = 0; q < 8; ++q) hh[q] = bf16_rne(f[q]);
            uint4 ph = { hh[0] | (hh[1]<<16), hh[2] | (hh[3]<<16),
                         hh[4] | (hh[5]<<16), hh[6] | (hh[7]<<16) };
            int off = woff + (((shalf*4 + g) ^ swz) * 8);
            *(uint4*)&sAh[off] = ph;
            *(uint4*)&sBh[off] = vbh[g];
        }
        __syncthreads();
        if (k0 < 448) {
            const int kn = k0 + 64;
#pragma unroll
            for (int g = 0; g < 4; ++g) {
                fa[g][0] = *(const float4*)(Ag + abase + kn + g*8);
                fa[g][1] = *(const float4*)(Ag + abase + kn + g*8 + 4);
                vbh[g]   = bok ? *(const uint4*)(Bhg + bbase + kn + g*8) : (uint4){0,0,0,0};
            }
        }
#pragma unroll
        for (int c = 0; c < 2; ++c) {
            const int ks = ((c*4 + (lane >> 4)) ^ (lane & 7)) * 8;
            bf16x8 fAh[4], fBh[4];
#pragma unroll
            for (int mi = 0; mi < 4; ++mi) {
                int ro = (mh*64 + mi*16 + (lane & 15)) * 64;
                fAh[mi] = *(const bf16x8*)&sAh[ro + ks];
            }
#pragma unroll
            for (int ni = 0; ni < 4; ++ni) {
                int ro = (nh*64 + ni*16 + (lane & 15)) * 64;
                fBh[ni] = *(const bf16x8*)&sBh[ro + ks];
            }
#pragma unroll
            for (int mi = 0; mi < 4; ++mi)
#pragma unroll
                for (int ni = 0; ni < 4; ++ni)
                    acc[mi][ni] = __builtin_amdgcn_mfma_f32_16x16x32_bf16(
                        fAh[mi], fBh[ni], acc[mi][ni], 0, 0, 0);
        }
    }

#pragma unroll
    for (int ni = 0; ni < 4; ++ni) {
        int gcol = c0 + nh*64 + ni*16 + (lane & 15);
        bool ok = gcol < N;
        float bias = ok ? bias0[gcol] : 0.f;
#pragma unroll
        for (int mi = 0; mi < 4; ++mi) {
            int grow = r0 + mh*64 + mi*16 + ((lane >> 4) << 2);
#pragma unroll
            for (int r = 0; r < 4; ++r)
                if (ok) C[(size_t)(grow + r) * ldc + gcol] = acc[mi][ni][r] + bias;
        }
    }
}

extern "C" void kernel_launch(void* const* d_in, const int* in_sizes, int n_in,
                              void* d_out, int out_size, void* d_ws, size_t ws_size,
                              hipStream_t stream) {
    const int*   inputs = (const int*)d_in[0];
    const float* hidden = (const float*)d_in[1];
    const float* emb    = (const float*)d_in[2];
    const float* W_ih0  = (const float*)d_in[3];
    const float* b_ih0  = (const float*)d_in[4];
    const float* W_hh0  = (const float*)d_in[5];
    const float* b_hh0  = (const float*)d_in[6];
    const float* W_in   = (const float*)d_in[7];
    const float* b_in   = (const float*)d_in[8];
    const float* W_hh   = (const float*)d_in[9];
    const float* b_hh   = (const float*)d_in[10];
    const float* Wy     = (const float*)d_in[11];
    const float* by     = (const float*)d_in[12];
    float* out = (float*)d_out;

    float* ws     = (float*)d_ws;
    float* pre0   = ws + PRE0_OFF;
    float* h0_all = ws + H0_OFF;
    float* h1_all = ws + H1_OFF;
    unsigned* flags = (unsigned*)(ws + FLAGS_OFF);
    float* out_hidden = out + LOGITS_N;
    const bool big_ws = (ws_size >= WS_NEED_FLOATS * 4ull);

    unsigned short* wy_hi   = (unsigned short*)(ws + CONV_OFF);
    unsigned short* wih0_hi = wy_hi + (size_t)VOC * HID;

    // 1) initial hidden state -> slot 0; zero flags + group queues
    init_state_k<<<dim3((BH + 255) / 256), dim3(256), 0, stream>>>(hidden, h0_all, h1_all, flags);

    const float* pre0_c = pre0;
    if (big_ws) {
        // 2) merged weight pre-split + pre0 (2-pass MFMA)
        split2_hi_k<<<dim3((VOC*HID/4 + HID*EMBD/4 + 255) / 256), dim3(256), 0, stream>>>(
            Wy, W_ih0, wy_hi, wih0_hi);
        gemm_mfma2f_k<<<dim3(64, 4), dim3(256), 0, stream>>>(
            emb, inputs, wih0_hi, b_ih0, b_hh0, pre0, HID, HID);

        // 3) recurrence v9 (XCD-grouped placement); fallback to v4 serial
        void* kargs9[] = { (void*)&pre0_c, (void*)&W_hh0, (void*)&W_in, (void*)&b_in,
                           (void*)&W_hh, (void*)&b_hh, (void*)&h0_all, (void*)&h1_all,
                           (void*)&flags };
        hipError_t e = hipLaunchCooperativeKernel((const void*)recurrence9_k,
                                                  dim3(384), dim3(512), kargs9, 0, stream);
        if (e != hipSuccess) {
            (void)hipGetLastError();
            hipLaunchCooperativeKernel((const void*)recurrence_k, dim3(192), dim3(512),
                                       kargs9, 0, stream);
        }

        // 4) final hidden -> d_out tail; 5) logits (serial 1-pass)
        copy_out_k<<<dim3(256), dim3(256), 0, stream>>>(h0_all, h1_all, out_hidden);
        gemm_mfma1f_k<<<dim3(64, 79), dim3(256), 0, stream>>>(
            h1_all + BH, wy_hi, by, out, VOC, VOC);
    } else {
        // small-ws fallback: fp32 GEMMs + serial recurrence
        gemm_nt_k<<<dim3(64, 4), dim3(256), 0, stream>>>(
            emb, inputs, W_ih0, b_ih0, b_hh0, pre0, HID, EMBD, HID);
        void* kargs[] = { (void*)&pre0_c, (void*)&W_hh0, (void*)&W_in, (void*)&b_in,
                          (void*)&W_hh, (void*)&b_hh, (void*)&h0_all, (void*)&h1_all,
                          (void*)&flags };
        hipLaunchCooperativeKernel((const void*)recurrence_k, dim3(192), dim3(512),
                                   kargs, 0, stream);
        copy_out_k<<<dim3(256), dim3(256), 0, stream>>>(h0_all, h1_all, out_hidden);
        gemm_nt_k<<<dim3(64, 79), dim3(256), 0, stream>>>(
            h1_all + BH, nullptr, Wy, nullptr, by, out, VOC, HID, VOC);
    }
}

// Round 18
// 1117.883 us; speedup vs baseline: 1.7614x; 1.0034x over previous
//
#include <hip/hip_runtime.h>
#include <hip/hip_bf16.h>

#define SEQ 128
#define BAT 64
#define VOC 10000
#define EMBD 512
#define HID 512
#define BH (BAT*HID)                  // 32768
// workspace layout (floats)
#define PRE0_OFF 0
#define H0_OFF   ((size_t)SEQ*BH)                 // pre0: 128*BH
#define H1_OFF   (H0_OFF + (size_t)(SEQ+1)*BH)
#define FLAGS_OFF (H1_OFF + (size_t)(SEQ+1)*BH)   // 256 uints: fl1[0..63], fl2[64..191], q[192..195]
#define CONV_OFF (FLAGS_OFF + 256)                // bf16 weight arrays
#define LOGITS_N ((size_t)SEQ*BAT*VOC)            // 81,920,000 (in d_out)
// conv region (ushorts): wy_hi 5,120,000 + wih0_hi 262,144
#define CONV_USHORTS 5382144ull
#define WS_NEED_FLOATS (CONV_OFF + CONV_USHORTS/2)

typedef __attribute__((ext_vector_type(8))) __bf16 bf16x8;
typedef __attribute__((ext_vector_type(4))) float f32x4;

__global__ __launch_bounds__(256) void init_state_k(const float* __restrict__ hidden,
                                                    float* __restrict__ h0_0,
                                                    float* __restrict__ h1_0,
                                                    unsigned* __restrict__ flags) {
    int i = blockIdx.x * 256 + threadIdx.x;
    if (i < 256) flags[i] = 0u;   // includes 4 group-queue counters at [192..195]
    if (i < BH) { h0_0[i] = hidden[i]; h1_0[i] = hidden[BH + i]; }
}

// fp32 GEMM fallback (only if ws too small for bf16-split path).
__global__ __launch_bounds__(256) void gemm_nt_k(
    const float* __restrict__ A, const int* __restrict__ tok,
    const float* __restrict__ Bm,
    const float* __restrict__ bias0, const float* __restrict__ bias1,
    float* __restrict__ C, int N, int K, int ldc)
{
    __shared__ float As[32][132];
    __shared__ float Bs[32][132];
    __shared__ int toks[128];

    const int tid = threadIdx.x;
    const int r0 = blockIdx.x * 128;
    const int c0 = blockIdx.y * 128;

    if (tok != nullptr && tid < 128) toks[tid] = tok[r0 + tid];
    __syncthreads();

    const int tn = tid & 15;
    const int tm = tid >> 4;
    const int m0 = tm * 8, n0 = tn * 8;

    float acc[8][8];
#pragma unroll
    for (int i = 0; i < 8; ++i)
#pragma unroll
        for (int j = 0; j < 8; ++j) acc[i][j] = 0.f;

    for (int k0 = 0; k0 < K; k0 += 32) {
#pragma unroll
        for (int p = 0; p < 4; ++p) {
            int idx = p * 256 + tid;
            int row = idx >> 3;
            int kq  = (idx & 7) << 2;
            size_t arow = tok ? (size_t)toks[row] : (size_t)(r0 + row);
            float4 a = *(const float4*)(A + arow * (size_t)K + k0 + kq);
            As[kq+0][row] = a.x; As[kq+1][row] = a.y;
            As[kq+2][row] = a.z; As[kq+3][row] = a.w;
            int gc = c0 + row;
            float4 b = make_float4(0.f, 0.f, 0.f, 0.f);
            if (gc < N) b = *(const float4*)(Bm + (size_t)gc * K + k0 + kq);
            Bs[kq+0][row] = b.x; Bs[kq+1][row] = b.y;
            Bs[kq+2][row] = b.z; Bs[kq+3][row] = b.w;
        }
        __syncthreads();
#pragma unroll 8
        for (int k = 0; k < 32; ++k) {
            float4 a0 = *(const float4*)&As[k][m0];
            float4 a1 = *(const float4*)&As[k][m0 + 4];
            float4 b0 = *(const float4*)&Bs[k][n0];
            float4 b1 = *(const float4*)&Bs[k][n0 + 4];
            float am[8] = {a0.x,a0.y,a0.z,a0.w,a1.x,a1.y,a1.z,a1.w};
            float bn[8] = {b0.x,b0.y,b0.z,b0.w,b1.x,b1.y,b1.z,b1.w};
#pragma unroll
            for (int i = 0; i < 8; ++i)
#pragma unroll
                for (int j = 0; j < 8; ++j) acc[i][j] += am[i] * bn[j];
        }
        __syncthreads();
    }

    const bool full = (c0 + 128 <= N);
#pragma unroll
    for (int i = 0; i < 8; ++i) {
        size_t r = (size_t)(r0 + m0 + i);
        float* crow = C + r * (size_t)ldc;
#pragma unroll
        for (int j = 0; j < 8; ++j) {
            int c = c0 + n0 + j;
            if (full || c < N) {
                float v = acc[i][j];
                if (bias0) v += bias0[c];
                if (bias1) v += bias1[c];
                crow[c] = v;
            }
        }
    }
}

#define BFLY(S, N)                                                     \
    {                                                                  \
        _Pragma("unroll")                                              \
        for (int i = 0; i < N; ++i) {                                  \
            float lo_ = a[i], hi_ = a[i + N];                          \
            float send_ = (lane & S) ? lo_ : hi_;                      \
            float recv_ = __shfl_xor(send_, S);                       \
            a[i] = ((lane & S) ? hi_ : lo_) + recv_;                   \
        }                                                              \
    }

__device__ __forceinline__ unsigned bf16_rne(float x) {
    unsigned u = __float_as_uint(x);
    unsigned r = u + 0x7fffu + ((u >> 16) & 1u);
    return r >> 16;
}

// ---- v4 recurrence body, task id 0..191. Stage loads use sc0 ONLY
// (L1-bypass, L2-ELIGIBLE; proven correct & perf-neutral in round 17's
// fallback run): a slot's lines are never read pre-flag by any agent, so no
// stale local-L2 copy can exist; an L2 miss falls through to L3 (fresh, since
// producer stores are sc1 write-through). With same-XCD group placement (v9
// below) the staged reads can hit the LOCAL L2. ----
__device__ __forceinline__ void recurrence_body(
    int blk,
    const float* __restrict__ pre0, const float* __restrict__ W_hh0,
    const float* __restrict__ W_in, const float* __restrict__ b_in,
    const float* __restrict__ W_hh, const float* __restrict__ b_hh,
    float* __restrict__ h0_all, float* __restrict__ h1_all,
    unsigned* __restrict__ flags, float* __restrict__ xs)
{
    const int tid  = threadIdx.x;
    const int lane = tid & 63;
    const int wv   = tid >> 6;
    const int p = ((lane&1)<<5)|((lane&2)<<3)|((lane&4)<<1)
                | ((lane&8)>>1)|((lane&16)>>3)|((lane&32)>>5);  // bitrev6
    const int b_own = p >> 3, j_own = p & 7;

    unsigned* fl1 = flags;
    unsigned* fl2 = flags + 64;

    float4 wr[8][2];
    float a[64];

    if (blk < 64) {                            // ---- layer 1 ----
        const int g = blk >> 4, jb = blk & 15;
        const int bt = wv & 1, jt = wv >> 1;
        const size_t win = (size_t)(g << 4) * HID;
#pragma unroll
        for (int jj = 0; jj < 8; ++jj) {
            const float* wp = W_hh0 + (size_t)(jb*32 + jt*8 + jj) * HID;
            wr[jj][0] = *(const float4*)(wp + lane*4);
            wr[jj][1] = *(const float4*)(wp + 256 + lane*4);
        }
        const unsigned* grp = fl1 + (g << 4);
        unsigned* myf = fl1 + (g << 4) + jb;
        const int bg = (g << 4) + (bt << 3) + b_own;
        const int jg = jb*32 + jt*8 + j_own;

        for (unsigned t = 1; t <= SEQ; ++t) {
            float pf = pre0[(size_t)(t-1)*BH + (size_t)bg*HID + jg];
            for (;;) {
                unsigned v = __hip_atomic_load(&grp[lane & 15], __ATOMIC_RELAXED,
                                               __HIP_MEMORY_SCOPE_AGENT);
                if (__ballot(v < (t - 1)) == 0ull) break;
            }
            __syncthreads();
            {
                const float4* src = (const float4*)(h0_all + (size_t)(t-1)*BH + win);
                float4 r0_, r1_, r2_, r3_;
                asm volatile("global_load_dwordx4 %0, %1, off sc0" : "=v"(r0_) : "v"(src + tid));
                asm volatile("global_load_dwordx4 %0, %1, off sc0" : "=v"(r1_) : "v"(src + tid + 512));
                asm volatile("global_load_dwordx4 %0, %1, off sc0" : "=v"(r2_) : "v"(src + tid + 1024));
                asm volatile("global_load_dwordx4 %0, %1, off sc0" : "=v"(r3_) : "v"(src + tid + 1536));
                asm volatile("s_waitcnt vmcnt(0)" ::: "memory");
                __builtin_amdgcn_sched_barrier(0);
                float4* dst = (float4*)xs;
                dst[tid] = r0_; dst[tid+512] = r1_; dst[tid+1024] = r2_; dst[tid+1536] = r3_;
            }
            __syncthreads();
#pragma unroll
            for (int i = 0; i < 64; ++i) a[i] = 0.f;
#pragma unroll
            for (int b = 0; b < 8; ++b) {
                const int row = (bt << 3) + b;
                float4 ha = *(const float4*)&xs[row*512 + lane*4];
                float4 hb = *(const float4*)&xs[row*512 + 256 + lane*4];
#pragma unroll
                for (int jj = 0; jj < 8; ++jj) {
                    a[b*8+jj] += ha.x*wr[jj][0].x + ha.y*wr[jj][0].y
                               + ha.z*wr[jj][0].z + ha.w*wr[jj][0].w
                               + hb.x*wr[jj][1].x + hb.y*wr[jj][1].y
                               + hb.z*wr[jj][1].z + hb.w*wr[jj][1].w;
                }
            }
            BFLY(1,32) BFLY(2,16) BFLY(4,8) BFLY(8,4) BFLY(16,2) BFLY(32,1)
            float v = tanhf(a[0] + pf);
            __hip_atomic_store(&h0_all[(size_t)t*BH + (size_t)bg*HID + jg], v,
                               __ATOMIC_RELAXED, __HIP_MEMORY_SCOPE_AGENT);
            asm volatile("s_waitcnt vmcnt(0)" ::: "memory");
            __syncthreads();
            if (tid == 0) __hip_atomic_store(myf, t, __ATOMIC_RELAXED,
                                             __HIP_MEMORY_SCOPE_AGENT);
        }
    } else {                                   // ---- layer 2 ----
        const int idx = blk - 64;
        const int g = idx >> 5, jb = idx & 31;
        const int bt = wv & 1, jt = (wv >> 1) & 1, kt = wv >> 2;
        const size_t win = (size_t)(g << 4) * HID;
        const float* Wmat = kt ? W_hh : W_in;
#pragma unroll
        for (int jj = 0; jj < 8; ++jj) {
            const float* wp = Wmat + (size_t)(jb*16 + jt*8 + jj) * HID;
            wr[jj][0] = *(const float4*)(wp + lane*4);
            wr[jj][1] = *(const float4*)(wp + 256 + lane*4);
        }
        const unsigned* grpA = fl1 + (g << 4);
        const unsigned* grpB = fl2 + (g << 5);
        unsigned* myf = fl2 + (g << 5) + jb;
        const int bg = (g << 4) + (bt << 3) + b_own;
        const int jg = jb*16 + jt*8 + j_own;
        const float bias = b_in[jg] + b_hh[jg];
        const int scx = (wv & 3) * 64 + lane;

        for (unsigned t = 1; t <= SEQ; ++t) {
            for (;;) {
                unsigned v1 = __hip_atomic_load(&grpA[lane & 15], __ATOMIC_RELAXED,
                                                __HIP_MEMORY_SCOPE_AGENT);
                unsigned v2 = __hip_atomic_load(&grpB[lane & 31], __ATOMIC_RELAXED,
                                                __HIP_MEMORY_SCOPE_AGENT);
                if (__ballot(v1 < t) == 0ull && __ballot(v2 < (t - 1)) == 0ull) break;
            }
            __syncthreads();
            {
                const int q = tid & 255;
                const float4* src = (tid < 256)
                    ? (const float4*)(h0_all + (size_t)t*BH + win)
                    : (const float4*)(h1_all + (size_t)(t-1)*BH + win);
                float4 rr[8];
#pragma unroll
                for (int i = 0; i < 8; ++i)
                    asm volatile("global_load_dwordx4 %0, %1, off sc0"
                                 : "=v"(rr[i]) : "v"(src + q + i*256));
                asm volatile("s_waitcnt vmcnt(0)" ::: "memory");
                __builtin_amdgcn_sched_barrier(0);
                float4* dst = (float4*)(xs + ((tid < 256) ? 0 : 8192));
#pragma unroll
                for (int i = 0; i < 8; ++i) dst[q + i*256] = rr[i];
            }
            __syncthreads();
#pragma unroll
            for (int i = 0; i < 64; ++i) a[i] = 0.f;
            const float* xsrc = xs + (kt ? 8192 : 0);
#pragma unroll
            for (int b = 0; b < 8; ++b) {
                const int row = (bt << 3) + b;
                float4 ha = *(const float4*)&xsrc[row*512 + lane*4];
                float4 hb = *(const float4*)&xsrc[row*512 + 256 + lane*4];
#pragma unroll
                for (int jj = 0; jj < 8; ++jj) {
                    a[b*8+jj] += ha.x*wr[jj][0].x + ha.y*wr[jj][0].y
                               + ha.z*wr[jj][0].z + ha.w*wr[jj][0].w
                               + hb.x*wr[jj][1].x + hb.y*wr[jj][1].y
                               + hb.z*wr[jj][1].z + hb.w*wr[jj][1].w;
                }
            }
            BFLY(1,32) BFLY(2,16) BFLY(4,8) BFLY(8,4) BFLY(16,2) BFLY(32,1)
            __syncthreads();
            if (kt) xs[scx] = a[0];
            __syncthreads();
            if (!kt) {
                float v = tanhf(a[0] + xs[scx] + bias);
                __hip_atomic_store(&h1_all[(size_t)t*BH + (size_t)bg*HID + jg], v,
                                   __ATOMIC_RELAXED, __HIP_MEMORY_SCOPE_AGENT);
            }
            asm volatile("s_waitcnt vmcnt(0)" ::: "memory");
            __syncthreads();
            if (tid == 0) __hip_atomic_store(myf, t, __ATOMIC_RELAXED,
                                             __HIP_MEMORY_SCOPE_AGENT);
        }
    }
}

// Standalone v4 (fallback path; placement-free, same body)
__global__ __launch_bounds__(512) void recurrence_k(
    const float* __restrict__ pre0, const float* __restrict__ W_hh0,
    const float* __restrict__ W_in, const float* __restrict__ b_in,
    const float* __restrict__ W_hh, const float* __restrict__ b_hh,
    float* __restrict__ h0_all, float* __restrict__ h1_all,
    unsigned* __restrict__ flags)
{
    __shared__ float xs[16384];
    recurrence_body(blockIdx.x, pre0, W_hh0, W_in, b_in, W_hh, b_hh,
                    h0_all, h1_all, flags, xs);
}

// ---------------- recurrence v9: XCD-grouped placement ----------------
// Round-17 post-mortem: plain __launch_bounds__(512) let VGPR float >128 ->
// occupancy 1 block/CU -> 384-block coop launch REJECTED -> fallback ran.
// Fix: (512, 2) caps VGPR at 128 (>= ~90 the body needs; proven no-spill at
// 128 in round 15) -> 2 blocks/CU -> 512 co-resident >= 384.
// Group g (g<4) = 48 tasks (16 L1 + 32 L2) with intra-group h traffic.
// XCD g<4 blocks claim group-g tasks immediately; others sleep ~3.4us then
// sweep leftovers (all 192 tasks provably claimed for any distribution).
__global__ __launch_bounds__(512, 2) void recurrence9_k(
    const float* __restrict__ pre0, const float* __restrict__ W_hh0,
    const float* __restrict__ W_in, const float* __restrict__ b_in,
    const float* __restrict__ W_hh, const float* __restrict__ b_hh,
    float* __restrict__ h0_all, float* __restrict__ h1_all,
    unsigned* __restrict__ flags)
{
    __shared__ float xs[16384];
    __shared__ int s_task;

    if (threadIdx.x == 0) {
        unsigned xcc;
        asm volatile("s_getreg_b32 %0, hwreg(20, 0, 4)" : "=s"(xcc));
        unsigned* q = flags + 192;    // 4 group queues
        int task = -1;
        if (xcc < 4u) {
            unsigned r = atomicAdd(&q[xcc], 1u);
            if (r < 48u) task = (r < 16u) ? (int)(xcc*16u + r)
                                          : (int)(64u + xcc*32u + (r - 16u));
        }
        if (task < 0) {
            __builtin_amdgcn_s_sleep(127);   // let home-XCD blocks claim first
            for (unsigned g = 0; g < 4u && task < 0; ++g) {
                unsigned r = atomicAdd(&q[g], 1u);
                if (r < 48u) task = (r < 16u) ? (int)(g*16u + r)
                                              : (int)(64u + g*32u + (r - 16u));
            }
        }
        s_task = task;
    }
    __syncthreads();
    const int task = s_task;
    if (task < 0) return;

    recurrence_body(task, pre0, W_hh0, W_in, b_in, W_hh, b_hh,
                    h0_all, h1_all, flags, xs);
}

__global__ __launch_bounds__(256) void copy_out_k(const float* __restrict__ h0_all,
                                                  const float* __restrict__ h1_all,
                                                  float* __restrict__ out_hidden) {
    int g = blockIdx.x * 256 + threadIdx.x;
    if (g < BH)            out_hidden[g] = h0_all[(size_t)SEQ * BH + g];
    else if (g < 2 * BH)   out_hidden[g] = h1_all[(size_t)SEQ * BH + (g - BH)];
}

// ---------------- bf16 weight pre-split (merged) + MFMA GEMMs ----------------

// One launch splits BOTH Wy (hi) and W_ih0 (hi).
__global__ __launch_bounds__(256) void split2_hi_k(const float* __restrict__ wy,
                                                   const float* __restrict__ wih0,
                                                   unsigned short* __restrict__ wy_hi,
                                                   unsigned short* __restrict__ wih0_hi) {
    const int n4a = VOC*HID/4;       // 1,280,000
    const int n4b = HID*EMBD/4;      //    65,536
    int i = blockIdx.x * 256 + threadIdx.x;
    const float* src; unsigned short* dst; int idx;
    if (i < n4a)            { src = wy;   dst = wy_hi;   idx = i; }
    else if (i < n4a + n4b) { src = wih0; dst = wih0_hi; idx = i - n4a; }
    else return;
    float4 v = ((const float4*)src)[idx];
    ushort4 h4;
    h4.x = (unsigned short)bf16_rne(v.x); h4.y = (unsigned short)bf16_rne(v.y);
    h4.z = (unsigned short)bf16_rne(v.z); h4.w = (unsigned short)bf16_rne(v.w);
    ((ushort4*)dst)[idx] = h4;
}

// 2-pass (A split hi/lo in-register): used for pre0 (feeds the recurrence).
__global__ __launch_bounds__(256) void gemm_mfma2f_k(
    const float* __restrict__ Ag, const int* __restrict__ tok,
    const unsigned short* __restrict__ Bhg,
    const float* __restrict__ bias0, const float* __restrict__ bias1,
    float* __restrict__ C, int N, int ldc)
{
    __shared__ __align__(16) unsigned short sAh[128*64];
    __shared__ __align__(16) unsigned short sAl[128*64];
    __shared__ __align__(16) unsigned short sBh[128*64];

    const int tid = threadIdx.x;
    const int flat = blockIdx.y * gridDim.x + blockIdx.x;
    const int cpx  = (gridDim.x * gridDim.y) >> 3;
    const int w    = (flat & 7) * cpx + (flat >> 3);
    const int r0 = (w & 63) * 128, c0 = (w >> 6) * 128;

    const int lane = tid & 63, wvv = tid >> 6;
    const int mh = wvv >> 1, nh = wvv & 1;

    f32x4 acc[4][4];
#pragma unroll
    for (int i = 0; i < 4; ++i)
#pragma unroll
        for (int j = 0; j < 4; ++j) acc[i][j] = (f32x4){0.f, 0.f, 0.f, 0.f};

    const int srow = tid >> 1, shalf = tid & 1;
    const size_t arow = tok ? (size_t)tok[r0 + srow] : (size_t)(r0 + srow);
    const size_t abase = arow * 512 + (size_t)shalf * 32;
    const int brow = c0 + srow;
    const bool bok = brow < N;
    const size_t bbase = (size_t)(bok ? brow : 0) * 512 + shalf * 32;
    const int woff = srow * 64;
    const int swz = srow & 7;

    float4 fa[4][2];
    uint4 vbh[4];
#pragma unroll
    for (int g = 0; g < 4; ++g) {
        fa[g][0] = *(const float4*)(Ag + abase + g*8);
        fa[g][1] = *(const float4*)(Ag + abase + g*8 + 4);
        vbh[g]   = bok ? *(const uint4*)(Bhg + bbase + g*8) : (uint4){0,0,0,0};
    }

    for (int k0 = 0; k0 < 512; k0 += 64) {
        __syncthreads();
#pragma unroll
        for (int g = 0; g < 4; ++g) {
            float f[8] = {fa[g][0].x, fa[g][0].y, fa[g][0].z, fa[g][0].w,
                          fa[g][1].x, fa[g][1].y, fa[g][1].z, fa[g][1].w};
            unsigned hh[8], ll[8];
#pragma unroll
            for (int q = 0; q < 8; ++q) {
                hh[q] = bf16_rne(f[q]);
                ll[q] = bf16_rne(f[q] - __uint_as_float(hh[q] << 16));
            }
            uint4 ph = { hh[0] | (hh[1]<<16), hh[2] | (hh[3]<<16),
                         hh[4] | (hh[5]<<16), hh[6] | (hh[7]<<16) };
            uint4 pl = { ll[0] | (ll[1]<<16), ll[2] | (ll[3]<<16),
                         ll[4] | (ll[5]<<16), ll[6] | (ll[7]<<16) };
            int off = woff + (((shalf*4 + g) ^ swz) * 8);
            *(uint4*)&sAh[off] = ph;
            *(uint4*)&sAl[off] = pl;
            *(uint4*)&sBh[off] = vbh[g];
        }
        __syncthreads();
        if (k0 < 448) {
            const int kn = k0 + 64;
#pragma unroll
            for (int g = 0; g < 4; ++g) {
                fa[g][0] = *(const float4*)(Ag + abase + kn + g*8);
                fa[g][1] = *(const float4*)(Ag + abase + kn + g*8 + 4);
                vbh[g]   = bok ? *(const uint4*)(Bhg + bbase + kn + g*8) : (uint4){0,0,0,0};
            }
        }
#pragma unroll
        for (int c = 0; c < 2; ++c) {
            const int ks = ((c*4 + (lane >> 4)) ^ (lane & 7)) * 8;
            bf16x8 fAh[4], fAl[4], fBh[4];
#pragma unroll
            for (int mi = 0; mi < 4; ++mi) {
                int ro = (mh*64 + mi*16 + (lane & 15)) * 64;
                fAh[mi] = *(const bf16x8*)&sAh[ro + ks];
                fAl[mi] = *(const bf16x8*)&sAl[ro + ks];
            }
#pragma unroll
            for (int ni = 0; ni < 4; ++ni) {
                int ro = (nh*64 + ni*16 + (lane & 15)) * 64;
                fBh[ni] = *(const bf16x8*)&sBh[ro + ks];
            }
#pragma unroll
            for (int mi = 0; mi < 4; ++mi)
#pragma unroll
                for (int ni = 0; ni < 4; ++ni) {
                    acc[mi][ni] = __builtin_amdgcn_mfma_f32_16x16x32_bf16(
                        fAh[mi], fBh[ni], acc[mi][ni], 0, 0, 0);
                    acc[mi][ni] = __builtin_amdgcn_mfma_f32_16x16x32_bf16(
                        fAl[mi], fBh[ni], acc[mi][ni], 0, 0, 0);
                }
        }
    }

#pragma unroll
    for (int ni = 0; ni < 4; ++ni) {
        int gcol = c0 + nh*64 + ni*16 + (lane & 15);
        bool ok = gcol < N;
        float bias = 0.f;
        if (ok) {
            if (bias0) bias += bias0[gcol];
            if (bias1) bias += bias1[gcol];
        }
#pragma unroll
        for (int mi = 0; mi < 4; ++mi) {
            int grow = r0 + mh*64 + mi*16 + ((lane >> 4) << 2);
#pragma unroll
            for (int r = 0; r < 4; ++r)
                if (ok) C[(size_t)(grow + r) * ldc + gcol] = acc[mi][ni][r] + bias;
        }
    }
}

// 1-pass logits GEMM (serial; A fp32 -> bf16 in-register, B pre-split bf16).
__global__ __launch_bounds__(256) void gemm_mfma1f_k(
    const float* __restrict__ Ag,
    const unsigned short* __restrict__ Bhg,
    const float* __restrict__ bias0,
    float* __restrict__ C, int N, int ldc)
{
    __shared__ __align__(16) unsigned short sAh[128*64];
    __shared__ __align__(16) unsigned short sBh[128*64];

    const int tid = threadIdx.x;
    const int flat = blockIdx.y * gridDim.x + blockIdx.x;
    const int cpx  = (gridDim.x * gridDim.y) >> 3;
    const int w    = (flat & 7) * cpx + (flat >> 3);
    const int r0 = (w & 63) * 128, c0 = (w >> 6) * 128;

    const int lane = tid & 63, wvv = tid >> 6;
    const int mh = wvv >> 1, nh = wvv & 1;

    f32x4 acc[4][4];
#pragma unroll
    for (int i = 0; i < 4; ++i)
#pragma unroll
        for (int j = 0; j < 4; ++j) acc[i][j] = (f32x4){0.f, 0.f, 0.f, 0.f};

    const int srow = tid >> 1, shalf = tid & 1;
    const size_t abase = (size_t)(r0 + srow) * 512 + (size_t)shalf * 32;
    const int brow = c0 + srow;
    const bool bok = brow < N;
    const size_t bbase = (size_t)(bok ? brow : 0) * 512 + shalf * 32;
    const int woff = srow * 64;
    const int swz = srow & 7;

    float4 fa[4][2];
    uint4 vbh[4];
#pragma unroll
    for (int g = 0; g < 4; ++g) {
        fa[g][0] = *(const float4*)(Ag + abase + g*8);
        fa[g][1] = *(const float4*)(Ag + abase + g*8 + 4);
        vbh[g]   = bok ? *(const uint4*)(Bhg + bbase + g*8) : (uint4){0,0,0,0};
    }

    for (int k0 = 0; k0 < 512; k0 += 64) {
        __syncthreads();
#pragma unroll
        for (int g = 0; g < 4; ++g) {
            float f[8] = {fa[g][0].x, fa[g][0].y, fa[g][0].z, fa[g][0].w,
                          fa[g][1].x, fa[g][1].y, fa[g][1].z, fa[g][1].w};
            unsigned hh[8];
#pragma unroll
            for (int q = 0; q < 8; ++q) hh[q] = bf16_rne(f[q]);
            uint4 ph = { hh[0] | (hh[1]<<16), hh[2] | (hh[3]<<16),
                         hh[4] | (hh[5]<<16), hh[6] | (hh[7]<<16) };
            int off = woff + (((shalf*4 + g) ^ swz) * 8);
            *(uint4*)&sAh[off] = ph;
            *(uint4*)&sBh[off] = vbh[g];
        }
        __syncthreads();
        if (k0 < 448) {
            const int kn = k0 + 64;
#pragma unroll
            for (int g = 0; g < 4; ++g) {
                fa[g][0] = *(const float4*)(Ag + abase + kn + g*8);
                fa[g][1] = *(const float4*)(Ag + abase + kn + g*8 + 4);
                vbh[g]   = bok ? *(const uint4*)(Bhg + bbase + kn + g*8) : (uint4){0,0,0,0};
            }
        }
#pragma unroll
        for (int c = 0; c < 2; ++c) {
            const int ks = ((c*4 + (lane >> 4)) ^ (lane & 7)) * 8;
            bf16x8 fAh[4], fBh[4];
#pragma unroll
            for (int mi = 0; mi < 4; ++mi) {
                int ro = (mh*64 + mi*16 + (lane & 15)) * 64;
                fAh[mi] = *(const bf16x8*)&sAh[ro + ks];
            }
#pragma unroll
            for (int ni = 0; ni < 4; ++ni) {
                int ro = (nh*64 + ni*16 + (lane & 15)) * 64;
                fBh[ni] = *(const bf16x8*)&sBh[ro + ks];
            }
#pragma unroll
            for (int mi = 0; mi < 4; ++mi)
#pragma unroll
                for (int ni = 0; ni < 4; ++ni)
                    acc[mi][ni] = __builtin_amdgcn_mfma_f32_16x16x32_bf16(
                        fAh[mi], fBh[ni], acc[mi][ni], 0, 0, 0);
        }
    }

#pragma unroll
    for (int ni = 0; ni < 4; ++ni) {
        int gcol = c0 + nh*64 + ni*16 + (lane & 15);
        bool ok = gcol < N;
        float bias = ok ? bias0[gcol] : 0.f;
#pragma unroll
        for (int mi = 0; mi < 4; ++mi) {
            int grow = r0 + mh*64 + mi*16 + ((lane >> 4) << 2);
#pragma unroll
            for (int r = 0; r < 4; ++r)
                if (ok) C[(size_t)(grow + r) * ldc + gcol] = acc[mi][ni][r] + bias;
        }
    }
}

extern "C" void kernel_launch(void* const* d_in, const int* in_sizes, int n_in,
                              void* d_out, int out_size, void* d_ws, size_t ws_size,
                              hipStream_t stream) {
    const int*   inputs = (const int*)d_in[0];
    const float* hidden = (const float*)d_in[1];
    const float* emb    = (const float*)d_in[2];
    const float* W_ih0  = (const float*)d_in[3];
    const float* b_ih0  = (const float*)d_in[4];
    const float* W_hh0  = (const float*)d_in[5];
    const float* b_hh0  = (const float*)d_in[6];
    const float* W_in   = (const float*)d_in[7];
    const float* b_in   = (const float*)d_in[8];
    const float* W_hh   = (const float*)d_in[9];
    const float* b_hh   = (const float*)d_in[10];
    const float* Wy     = (const float*)d_in[11];
    const float* by     = (const float*)d_in[12];
    float* out = (float*)d_out;

    float* ws     = (float*)d_ws;
    float* pre0   = ws + PRE0_OFF;
    float* h0_all = ws + H0_OFF;
    float* h1_all = ws + H1_OFF;
    unsigned* flags = (unsigned*)(ws + FLAGS_OFF);
    float* out_hidden = out + LOGITS_N;
    const bool big_ws = (ws_size >= WS_NEED_FLOATS * 4ull);

    unsigned short* wy_hi   = (unsigned short*)(ws + CONV_OFF);
    unsigned short* wih0_hi = wy_hi + (size_t)VOC * HID;

    // 1) initial hidden state -> slot 0; zero flags + group queues
    init_state_k<<<dim3((BH + 255) / 256), dim3(256), 0, stream>>>(hidden, h0_all, h1_all, flags);

    const float* pre0_c = pre0;
    if (big_ws) {
        // 2) merged weight pre-split + pre0 (2-pass MFMA)
        split2_hi_k<<<dim3((VOC*HID/4 + HID*EMBD/4 + 255) / 256), dim3(256), 0, stream>>>(
            Wy, W_ih0, wy_hi, wih0_hi);
        gemm_mfma2f_k<<<dim3(64, 4), dim3(256), 0, stream>>>(
            emb, inputs, wih0_hi, b_ih0, b_hh0, pre0, HID, HID);

        // 3) recurrence v9 (XCD-grouped placement, launch-bound fixed);
        //    fallback to v4 serial on launch rejection
        void* kargs9[] = { (void*)&pre0_c, (void*)&W_hh0, (void*)&W_in, (void*)&b_in,
                           (void*)&W_hh, (void*)&b_hh, (void*)&h0_all, (void*)&h1_all,
                           (void*)&flags };
        hipError_t e = hipLaunchCooperativeKernel((const void*)recurrence9_k,
                                                  dim3(384), dim3(512), kargs9, 0, stream);
        if (e != hipSuccess) {
            (void)hipGetLastError();
            hipLaunchCooperativeKernel((const void*)recurrence_k, dim3(192), dim3(512),
                                       kargs9, 0, stream);
        }

        // 4) final hidden -> d_out tail; 5) logits (serial 1-pass)
        copy_out_k<<<dim3(256), dim3(256), 0, stream>>>(h0_all, h1_all, out_hidden);
        gemm_mfma1f_k<<<dim3(64, 79), dim3(256), 0, stream>>>(
            h1_all + BH, wy_hi, by, out, VOC, VOC);
    } else {
        // small-ws fallback: fp32 GEMMs + serial recurrence
        gemm_nt_k<<<dim3(64, 4), dim3(256), 0, stream>>>(
            emb, inputs, W_ih0, b_ih0, b_hh0, pre0, HID, EMBD, HID);
        void* kargs[] = { (void*)&pre0_c, (void*)&W_hh0, (void*)&W_in, (void*)&b_in,
                          (void*)&W_hh, (void*)&b_hh, (void*)&h0_all, (void*)&h1_all,
                          (void*)&flags };
        hipLaunchCooperativeKernel((const void*)recurrence_k, dim3(192), dim3(512),
                                   kargs, 0, stream);
        copy_out_k<<<dim3(256), dim3(256), 0, stream>>>(h0_all, h1_all, out_hidden);
        gemm_nt_k<<<dim3(64, 79), dim3(256), 0, stream>>>(
            h1_all + BH, nullptr, Wy, nullptr, by, out, VOC, HID, VOC);
    }
}